// Round 1
// baseline (171.090 us; speedup 1.0000x reference)
//
#include <hip/hip_runtime.h>
#include <cstddef>

// QuadTree attention, 3 levels. B=4, C=128, NHEAD=8, d=16.
// Grids: 16x16 (S=256), 32x32 (S=1024), 64x64 (S=4096). TOPKS=(16,8,8).
//
// R10: un-pair subtrees — 1 subtree per wave, grid 2048 blocks x 4 waves
// = 8192 waves = 32 waves/CU cap (was 16). Arena halves to 4480B/wave ->
// 17920B/block -> 8 blocks/CU under the 160KB LDS cap; launch_bounds(256,8)
// keeps VGPR<=64 for 8 waves/SIMD. TLP replaces R9's twin-context ILP to
// hide gather latency + serial DPP top-k chains (VALUBusy was 53%).
// XCD swizzle id&7=(b<<1)|nh keeps per-XCD KV working set (~2.7MB) in the
// 4MB XCD L2 (256 blocks per (b,nh) = 32 CUs x 8 blocks on one XCD).

#define DPP_QUAD_X1 0xB1
#define DPP_QUAD_X2 0x4E
#define DPP_ROR_1   0x121
#define DPP_ROR_2   0x122
#define DPP_ROR_4   0x124
#define DPP_ROR_8   0x128

template<int C>
__device__ __forceinline__ int dpp_i(int x) {
    return __builtin_amdgcn_mov_dpp(x, C, 0xF, 0xF, true);
}
template<int C>
__device__ __forceinline__ float dpp_f(float x) {
    return __int_as_float(__builtin_amdgcn_mov_dpp(__float_as_int(x), C, 0xF, 0xF, true));
}
__device__ __forceinline__ float rowmax16(float x) {
    x = fmaxf(x, dpp_f<DPP_ROR_1>(x));
    x = fmaxf(x, dpp_f<DPP_ROR_2>(x));
    x = fmaxf(x, dpp_f<DPP_ROR_4>(x));
    x = fmaxf(x, dpp_f<DPP_ROR_8>(x));
    return x;
}
__device__ __forceinline__ int rowmin16i(int x) {
    { int o = dpp_i<DPP_ROR_1>(x); x = o < x ? o : x; }
    { int o = dpp_i<DPP_ROR_2>(x); x = o < x ? o : x; }
    { int o = dpp_i<DPP_ROR_4>(x); x = o < x ? o : x; }
    { int o = dpp_i<DPP_ROR_8>(x); x = o < x ? o : x; }
    return x;
}
__device__ __forceinline__ float quadmax4(float x) {
    x = fmaxf(x, dpp_f<DPP_QUAD_X1>(x));
    x = fmaxf(x, dpp_f<DPP_QUAD_X2>(x));
    return x;
}
__device__ __forceinline__ float quadsum4(float x) {
    x += dpp_f<DPP_QUAD_X1>(x);
    x += dpp_f<DPP_QUAD_X2>(x);
    return x;
}
__device__ __forceinline__ float wavemax(float x) {
    x = rowmax16(x);
    x = fmaxf(x, __shfl_xor(x, 16));
    x = fmaxf(x, __shfl_xor(x, 32));
    return x;
}
__device__ __forceinline__ float wavesum(float x) {
    x += dpp_f<DPP_ROR_1>(x); x += dpp_f<DPP_ROR_2>(x);
    x += dpp_f<DPP_ROR_4>(x); x += dpp_f<DPP_ROR_8>(x);
    x += __shfl_xor(x, 16);   x += __shfl_xor(x, 32);
    return x;
}
__device__ __forceinline__ float dot16(const float* __restrict__ qp, const float* kr) {
    float s = 0.f;
    #pragma unroll
    for (int i = 0; i < 4; ++i) {
        float4 a = *(const float4*)(qp + i*4);
        s = fmaf(a.x, kr[i*4+0], s);
        s = fmaf(a.y, kr[i*4+1], s);
        s = fmaf(a.z, kr[i*4+2], s);
        s = fmaf(a.w, kr[i*4+3], s);
    }
    return s;
}
__device__ __forceinline__ int child32(int s, int c) {
    return (((s >> 4)*2 + (c >> 1)) << 5) + ((s & 15)*2 + (c & 1));
}
__device__ __forceinline__ int child64(int g, int c) {
    return (((g >> 5)*2 + (c >> 1)) << 6) + ((g & 31)*2 + (c & 1));
}

// per-wave arena layout (floats)
#define W0V  560
#define W0P  576
#define MSG0 592
#define MSG1 608
#define W1V  672
#define W1P  704
#define GT   736
#define OUTT 864
#define ARENA 1120

// ---------------- Repack: head-major Q + KV-interleaved ----------------
__global__ __launch_bounds__(256) void k_repack(
    const float* __restrict__ q1, const float* __restrict__ k1, const float* __restrict__ v1,
    const float* __restrict__ q2, const float* __restrict__ k2, const float* __restrict__ v2,
    float* __restrict__ Q1h, float* __restrict__ KV1,
    float* __restrict__ Q2h, float* __restrict__ KV2)
{
    const int x = blockIdx.x, n = blockIdx.y, b = blockIdx.z;
    const int t = threadIdx.x;
    __shared__ float tA[16][129];
    __shared__ float tB[16][129];

    if (x < 20) {
        const float* src; float* dst; int S, ck;
        if (x < 4) { src = q1; dst = Q1h; S = 1024; ck = x; }
        else       { src = q2; dst = Q2h; S = 4096; ck = x - 4; }
        const int tok0 = ck * 256;
        const float* sp = src + ((size_t)(b*128 + n*16))*S + tok0;
        const int col = t & 127, half = t >> 7;
        #pragma unroll
        for (int j = 0; j < 8; ++j) {
            const int row = j*2 + half;
            tA[row][col] = sp[(size_t)row*S + col];
            tB[row][col] = sp[(size_t)row*S + col + 128];
        }
        __syncthreads();
        float* dp = dst + ((size_t)((b*8 + n)*S) + tok0 + t)*16;
        #pragma unroll
        for (int i = 0; i < 4; ++i) {
            float4 o;
            o.x = (half ? tB : tA)[i*4+0][col];
            o.y = (half ? tB : tA)[i*4+1][col];
            o.z = (half ? tB : tA)[i*4+2][col];
            o.w = (half ? tB : tA)[i*4+3][col];
            *(float4*)(dp + i*4) = o;
        }
    } else {
        const float* sK; const float* sV; float* dst; int S, ck;
        if (x < 28) { sK = k1; sV = v1; dst = KV1; S = 1024; ck = x - 20; }
        else        { sK = k2; sV = v2; dst = KV2; S = 4096; ck = x - 28; }
        const int tok0 = ck * 128;
        const int col = t & 127, rp = t >> 7;
        const float* kp = sK + ((size_t)(b*128 + n*16))*S + tok0;
        const float* vp = sV + ((size_t)(b*128 + n*16))*S + tok0;
        #pragma unroll
        for (int j = 0; j < 8; ++j) {
            const int row = j*2 + rp;
            tA[row][col] = kp[(size_t)row*S + col];
            tB[row][col] = vp[(size_t)row*S + col];
        }
        __syncthreads();
        const int tok = t >> 1, half = t & 1;
        float* dp = dst + (((size_t)((b*8 + n)*S) + tok0 + tok))*32 + half*16;
        #pragma unroll
        for (int i = 0; i < 4; ++i) {
            float4 o;
            o.x = (half ? tB : tA)[i*4+0][tok];
            o.y = (half ? tB : tA)[i*4+1][tok];
            o.z = (half ? tB : tA)[i*4+2][tok];
            o.w = (half ? tB : tA)[i*4+3][tok];
            *(float4*)(dp + i*4) = o;
        }
    }
}

// ---------------- Fused 3-level subtree kernel, 1 subtree/wave ---------
// grid (2048,1,1) x 256. id = (l0<<3) | (b<<1) | nh.
__global__ __launch_bounds__(256, 8) void k_fused(
    const float* __restrict__ q0, const float* __restrict__ k0, const float* __restrict__ v0,
    const float* __restrict__ Q1h, const float* __restrict__ KV1,
    const float* __restrict__ Q2h, const float* __restrict__ KV2,
    float* __restrict__ out)
{
    const int tid = threadIdx.x, lane = tid & 63, wid = tid >> 6;
    const int id = blockIdx.x;
    const int nh = id & 1;
    const int b  = (id >> 1) & 3;
    const int l0 = id >> 3;                  // 0..255
    const int n  = nh*4 + wid;
    const int H0 = l0 >> 4, W0 = l0 & 15;

    __shared__ float arenaAll[4][ARENA];
    float* const A = arenaAll[wid];

    const float* Q1hh = Q1h + (size_t)((b*8 + n)*1024)*16;
    const float* KV1h = KV1 + (size_t)((b*8 + n)*1024)*32;
    const float* Q2hh = Q2h + (size_t)((b*8 + n)*4096)*16;
    const float* KV2h = KV2 + (size_t)((b*8 + n)*4096)*32;

    // ======== stage A: lvl0 scores ========
    const float* qb = q0 + ((size_t)(b*128 + n*16))*256 + l0;
    const float* kb = k0 + ((size_t)(b*128 + n*16))*256 + lane*4;
    float qr[16];
    #pragma unroll
    for (int dd = 0; dd < 16; ++dd) qr[dd] = qb[(size_t)dd*256];
    float p[4] = {0.f,0.f,0.f,0.f};
    #pragma unroll
    for (int dd = 0; dd < 16; ++dd) {
        float4 kv = *(const float4*)(kb + (size_t)dd*256);
        p[0] = fmaf(qr[dd], kv.x, p[0]);
        p[1] = fmaf(qr[dd], kv.y, p[1]);
        p[2] = fmaf(qr[dd], kv.z, p[2]);
        p[3] = fmaf(qr[dd], kv.w, p[3]);
    }
    #pragma unroll
    for (int j = 0; j < 4; ++j) p[j] *= 0.25f;
    float mA = fmaxf(fmaxf(p[0], p[1]), fmaxf(p[2], p[3]));
    mA = wavemax(mA);
    float lsA = 0.f;
    #pragma unroll
    for (int j = 0; j < 4; ++j) { p[j] = expf(p[j] - mA); lsA += p[j]; }
    const float invA = 1.f / wavesum(lsA);
    #pragma unroll
    for (int j = 0; j < 4; ++j) p[j] *= invA;

    const int li = lane & 15;

    // ======== stage B: top-16 of 256 (per-row top-16, then rank merge) ====
    float w[4];
    #pragma unroll
    for (int j = 0; j < 4; ++j) w[j] = p[j];
    float cv = 0.f; int cpos = 0;
    #pragma unroll 1
    for (int it = 0; it < 16; ++it) {
        float bv = fmaxf(fmaxf(w[0], w[1]), fmaxf(w[2], w[3]));
        bv = rowmax16(bv);
        int cs = 0x7FFFFFFF;
        cs = (w[3] == bv) ? (lane*4 + 3) : cs;
        cs = (w[2] == bv) ? (lane*4 + 2) : cs;
        cs = (w[1] == bv) ? (lane*4 + 1) : cs;
        cs = (w[0] == bv) ? (lane*4 + 0) : cs;
        cs = rowmin16i(cs);
        w[0] = (cs == lane*4 + 0) ? 0.f : w[0];
        w[1] = (cs == lane*4 + 1) ? 0.f : w[1];
        w[2] = (cs == lane*4 + 2) ? 0.f : w[2];
        w[3] = (cs == lane*4 + 3) ? 0.f : w[3];
        if (li == it) { cv = bv; cpos = cs; }
    }
    // rank merge
    A[lane]      = cv;
    A[64 + lane] = __int_as_float(cpos);
    *(float4*)&A[288 + lane*4] = make_float4(0.f, 0.f, 0.f, 0.f);
    {
        const float cu = cv; const int pu = cpos;
        int rank = 0;
        #pragma unroll
        for (int jj = 0; jj < 16; ++jj) {
            float4 vv = *(const float4*)&A[jj*4];
            float4 pw = *(const float4*)&A[64 + jj*4];
            const int p0i = __float_as_int(pw.x), p1i = __float_as_int(pw.y);
            const int p2i = __float_as_int(pw.z), p3i = __float_as_int(pw.w);
            rank += (vv.x > cu || (vv.x == cu && p0i < pu)) ? 1 : 0;
            rank += (vv.y > cu || (vv.y == cu && p1i < pu)) ? 1 : 0;
            rank += (vv.z > cu || (vv.z == cu && p2i < pu)) ? 1 : 0;
            rank += (vv.w > cu || (vv.w == cu && p3i < pu)) ? 1 : 0;
        }
        if (rank < 16) {
            A[W0V + rank] = cu;
            A[W0P + rank] = __int_as_float(pu);
            A[288 + pu]   = 1.0f;
        }
    }
    {   // apply mask + padded store
        float4 fA = *(const float4*)&A[288 + lane*4];
        p[0] = (fA.x != 0.f) ? 0.f : p[0];
        p[1] = (fA.y != 0.f) ? 0.f : p[1];
        p[2] = (fA.z != 0.f) ? 0.f : p[2];
        p[3] = (fA.w != 0.f) ? 0.f : p[3];
        const int pad = lane*4 + 4*(lane>>4);
        *(float4*)&A[pad] = make_float4(p[0], p[1], p[2], p[3]);
    }

    // ======== early lvl1 child table + K prefetch ========
    float kr1[16];
    float psD;
    {
        const int kp = lane >> 2, ci = lane & 3;
        psD = A[W0V + kp];
        const int spos = __float_as_int(A[W0P + kp]);
        const int g1 = child32(spos, ci);
        A[GT + lane] = __int_as_float(g1);
        const float* kv = KV1h + (size_t)g1*32;
        #pragma unroll
        for (int i = 0; i < 4; ++i) *(float4*)&kr1[i*4] = *(const float4*)(kv + i*4);
    }

    // ======== stage C: msg0 ========
    {
        const int dd = lane & 15, chunk = lane >> 4;
        const float* vb = v0 + ((size_t)(b*128 + n*16 + dd))*256 + chunk*64;
        float a0 = 0.f;
        #pragma unroll
        for (int jj = 0; jj < 16; ++jj) {
            float4 vv = *(const float4*)(vb + jj*4);
            float4 p0 = *(const float4*)&A[chunk*68 + jj*4];
            a0 = fmaf(p0.x, vv.x, a0); a0 = fmaf(p0.y, vv.y, a0);
            a0 = fmaf(p0.z, vv.z, a0); a0 = fmaf(p0.w, vv.w, a0);
        }
        a0 += __shfl_xor(a0, 16); a0 += __shfl_xor(a0, 32);
        if (lane < 16) A[MSG0 + dd] = a0;
    }

    // ======== stage D: lvl1 scoring (kr1 preloaded) + top-8 ========
    #pragma unroll
    for (int t = 0; t < 4; ++t) {
        const int qtok = ((2*H0 + (t>>1)) << 5) + 2*W0 + (t&1);
        float sc = dot16(Q1hh + qtok*16, kr1) * 0.25f;
        const float mm = quadmax4(sc);
        const float e  = expf(sc - mm);
        const float su = quadsum4(e);
        A[288 + t*68 + lane] = (e / su) * psD;
    }
    {
        const int tg = lane >> 4;
        float r[4];
        {
            float4 t0 = *(const float4*)&A[288 + tg*68 + li*4];
            r[0] = t0.x; r[1] = t0.y; r[2] = t0.z; r[3] = t0.w;
        }
        float cv1 = 0.f; int cs1 = 0;
        #pragma unroll 1
        for (int it = 0; it < 8; ++it) {
            float bv = fmaxf(fmaxf(r[0], r[1]), fmaxf(r[2], r[3]));
            bv = rowmax16(bv);
            int cs = 0x7FFFFFFF;
            cs = (r[3] == bv) ? (li*4 + 3) : cs;
            cs = (r[2] == bv) ? (li*4 + 2) : cs;
            cs = (r[1] == bv) ? (li*4 + 1) : cs;
            cs = (r[0] == bv) ? (li*4 + 0) : cs;
            cs = rowmin16i(cs);
            r[0] = (cs == li*4 + 0) ? 0.f : r[0];
            r[1] = (cs == li*4 + 1) ? 0.f : r[1];
            r[2] = (cs == li*4 + 2) ? 0.f : r[2];
            r[3] = (cs == li*4 + 3) ? 0.f : r[3];
            if (li == it) { cv1 = bv; cs1 = cs; }
        }
        *(float4*)&A[288 + tg*68 + li*4] = make_float4(r[0], r[1], r[2], r[3]);
        if (li < 8) {
            A[W1V + tg*8 + li] = cv1;
            A[W1P + tg*8 + li] = A[GT + cs1];
        }
    }

    // ======== stage E: msg1 ========
    {
        const int ks = lane >> 4, t2 = (lane >> 2) & 3, dq = lane & 3;
        float4 acc = make_float4(0.f, 0.f, 0.f, 0.f);
        #pragma unroll
        for (int jj = 0; jj < 4; ++jj) {
            float4 pv = *(const float4*)&A[288 + t2*68 + ks*16 + jj*4];
            const float pa[4] = {pv.x, pv.y, pv.z, pv.w};
            #pragma unroll
            for (int c = 0; c < 4; ++c) {
                const int g = __float_as_int(A[GT + ks*16 + jj*4 + c]);
                float4 vv = *(const float4*)(KV1h + (size_t)g*32 + 16 + dq*4);
                acc.x = fmaf(pa[c], vv.x, acc.x);
                acc.y = fmaf(pa[c], vv.y, acc.y);
                acc.z = fmaf(pa[c], vv.z, acc.z);
                acc.w = fmaf(pa[c], vv.w, acc.w);
            }
        }
        acc.x += __shfl_xor(acc.x, 16); acc.y += __shfl_xor(acc.y, 16);
        acc.z += __shfl_xor(acc.z, 16); acc.w += __shfl_xor(acc.w, 16);
        acc.x += __shfl_xor(acc.x, 32); acc.y += __shfl_xor(acc.y, 32);
        acc.z += __shfl_xor(acc.z, 32); acc.w += __shfl_xor(acc.w, 32);
        if (lane < 16)
            *(float4*)&A[MSG1 + t2*16 + dq*4] = acc;
    }

    // ======== stage F: lvl2 ========
    {
        const int t1h = lane >> 5, kk = lane & 31;
        const int kp2 = kk >> 2, ci2 = kk & 3;
        float krA[16], krB[16];
        float psA, psB;
        // GT fill + all K loads up front (one wall)
        const int gA = child64(__float_as_int(A[W1P + t1h*8 + kp2]), ci2);
        const int gB = child64(__float_as_int(A[W1P + (2+t1h)*8 + kp2]), ci2);
        A[GT + t1h*32 + kk]     = __int_as_float(gA);
        A[GT + (2+t1h)*32 + kk] = __int_as_float(gB);
        psA = A[W1V + t1h*8 + kp2];
        psB = A[W1V + (2+t1h)*8 + kp2];
        const float* kva = KV2h + (size_t)gA*32;
        const float* kvb = KV2h + (size_t)gB*32;
        #pragma unroll
        for (int i = 0; i < 4; ++i) {
            *(float4*)&krA[i*4] = *(const float4*)(kva + i*4);
            *(float4*)&krB[i*4] = *(const float4*)(kvb + i*4);
        }
        // score pass 0 (t1 = t1h) and pass 1 (t1 = 2+t1h)
        {
            const int t1 = t1h;
            const int y1 = 2*H0 + (t1 >> 1), x1 = 2*W0 + (t1 & 1);
            #pragma unroll
            for (int t2 = 0; t2 < 4; ++t2) {
                const int qtok2 = ((2*y1 + (t2>>1)) << 6) + 2*x1 + (t2&1);
                float sc = dot16(Q2hh + qtok2*16, krA) * 0.25f;
                const float mm = quadmax4(sc);
                const float e  = expf(sc - mm);
                const float su = quadsum4(e);
                A[t1h*144 + t2*36 + kk] = (e / su) * psA;
            }
        }
        {
            const int t1 = 2 + t1h;
            const int y1 = 2*H0 + (t1 >> 1), x1 = 2*W0 + (t1 & 1);
            #pragma unroll
            for (int t2 = 0; t2 < 4; ++t2) {
                const int qtok2 = ((2*y1 + (t2>>1)) << 6) + 2*x1 + (t2&1);
                float sc = dot16(Q2hh + qtok2*16, krB) * 0.25f;
                const float mm = quadmax4(sc);
                const float e  = expf(sc - mm);
                const float su = quadsum4(e);
                A[288 + t1h*144 + t2*36 + kk] = (e / su) * psB;
            }
        }
    }
    // msg halves
    {
        const int ks2 = lane >> 5, qq = (lane >> 2) & 7, dq = lane & 3;
        const int t1l = qq >> 2, t2 = qq & 3;
        #pragma unroll
        for (int h = 0; h < 2; ++h) {
            const int t1 = h*2 + t1l;
            const int sb = (t1 >> 1)*288 + (t1 & 1)*144 + t2*36;
            float4 acc = make_float4(0.f, 0.f, 0.f, 0.f);
            #pragma unroll
            for (int j4 = 0; j4 < 4; ++j4) {
                float4 pv = *(const float4*)&A[sb + ks2*16 + j4*4];
                const float pa[4] = {pv.x, pv.y, pv.z, pv.w};
                #pragma unroll
                for (int c = 0; c < 4; ++c) {
                    const int g2 = __float_as_int(A[GT + t1*32 + ks2*16 + j4*4 + c]);
                    float4 vv = *(const float4*)(KV2h + (size_t)g2*32 + 16 + dq*4);
                    acc.x = fmaf(pa[c], vv.x, acc.x);
                    acc.y = fmaf(pa[c], vv.y, acc.y);
                    acc.z = fmaf(pa[c], vv.z, acc.z);
                    acc.w = fmaf(pa[c], vv.w, acc.w);
                }
            }
            acc.x += __shfl_xor(acc.x, 32); acc.y += __shfl_xor(acc.y, 32);
            acc.z += __shfl_xor(acc.z, 32); acc.w += __shfl_xor(acc.w, 32);
            if (lane < 32) {
                float4 m1 = *(const float4*)&A[MSG1 + t1*16 + dq*4];
                float4 m0 = *(const float4*)&A[MSG0 + dq*4];
                acc.x += m1.x + m0.x;
                acc.y += m1.y + m0.y;
                acc.z += m1.z + m0.z;
                acc.w += m1.w + m0.w;
                *(float4*)&A[OUTT + (t1*4 + t2)*16 + dq*4] = acc;
            }
        }
    }

    // ======== output: one 4x4 patch ========
    {
        const int y = lane & 3, dd = lane >> 2;
        float vr[4];
        #pragma unroll
        for (int x = 0; x < 4; ++x) {
            const int t1 = (((y>>1) << 1) | (x>>1));
            const int t2 = (((y&1)  << 1) | (x&1));
            vr[x] = A[OUTT + (t1*4 + t2)*16 + dd];
        }
        float* op = out + (((size_t)(b*128 + n*16 + dd)*64 + 4*H0 + y))*64 + 4*W0;
        *(float4*)op = make_float4(vr[0], vr[1], vr[2], vr[3]);
    }
}

extern "C" void kernel_launch(void* const* d_in, const int* in_sizes, int n_in,
                              void* d_out, int out_size, void* d_ws, size_t ws_size,
                              hipStream_t stream)
{
    const float* q0 = (const float*)d_in[0];
    const float* k0 = (const float*)d_in[1];
    const float* v0 = (const float*)d_in[2];
    const float* q1 = (const float*)d_in[3];
    const float* k1 = (const float*)d_in[4];
    const float* v1 = (const float*)d_in[5];
    const float* q2 = (const float*)d_in[6];
    const float* k2 = (const float*)d_in[7];
    const float* v2 = (const float*)d_in[8];

    float* ws  = (float*)d_ws;
    float* Q1h = ws;                 // 4*8*1024*16 = 524288
    float* KV1 = ws + 524288;        // 4*8*1024*32 = 1048576
    float* Q2h = ws + 1572864;       // 4*8*4096*16 = 2097152
    float* KV2 = ws + 3670016;       // 4*8*4096*32 = 4194304

    k_repack<<<dim3(60, 8, 4), 256, 0, stream>>>(q1, k1, v1, q2, k2, v2,
                                                 Q1h, KV1, Q2h, KV2);
    k_fused<<<dim3(2048, 1, 1), 256, 0, stream>>>(q0, k0, v0,
                                                  Q1h, KV1, Q2h, KV2,
                                                  (float*)d_out);
}

// Round 2
// 168.659 us; speedup vs baseline: 1.0144x; 1.0144x over previous
//
#include <hip/hip_runtime.h>
#include <cstddef>

// QuadTree attention, 3 levels. B=4, C=128, NHEAD=8, d=16.
// Grids: 16x16 (S=256), 32x32 (S=1024), 64x64 (S=4096). TOPKS=(16,8,8).
//
// R11: 1 subtree/wave (R10 structure) but __launch_bounds__(256, 6).
// R10's (256,8) forced VGPR=32 -> scratch spills (~12MB extra writes,
// WRITE_SIZE 8.3->20.1MB) which inserted memory round-trips into the
// latency-bound critical path (VALUBusy 53->46). Budget of ~85 VGPRs
// removes the spill; if the allocator lands <=64 the HW still reaches
// 8 waves/SIMD (LDS 17920B/block allows 8 blocks/CU).
// XCD swizzle id&7=(b<<1)|nh keeps per-XCD KV working set in XCD L2.

#define DPP_QUAD_X1 0xB1
#define DPP_QUAD_X2 0x4E
#define DPP_ROR_1   0x121
#define DPP_ROR_2   0x122
#define DPP_ROR_4   0x124
#define DPP_ROR_8   0x128

template<int C>
__device__ __forceinline__ int dpp_i(int x) {
    return __builtin_amdgcn_mov_dpp(x, C, 0xF, 0xF, true);
}
template<int C>
__device__ __forceinline__ float dpp_f(float x) {
    return __int_as_float(__builtin_amdgcn_mov_dpp(__float_as_int(x), C, 0xF, 0xF, true));
}
__device__ __forceinline__ float rowmax16(float x) {
    x = fmaxf(x, dpp_f<DPP_ROR_1>(x));
    x = fmaxf(x, dpp_f<DPP_ROR_2>(x));
    x = fmaxf(x, dpp_f<DPP_ROR_4>(x));
    x = fmaxf(x, dpp_f<DPP_ROR_8>(x));
    return x;
}
__device__ __forceinline__ int rowmin16i(int x) {
    { int o = dpp_i<DPP_ROR_1>(x); x = o < x ? o : x; }
    { int o = dpp_i<DPP_ROR_2>(x); x = o < x ? o : x; }
    { int o = dpp_i<DPP_ROR_4>(x); x = o < x ? o : x; }
    { int o = dpp_i<DPP_ROR_8>(x); x = o < x ? o : x; }
    return x;
}
__device__ __forceinline__ float quadmax4(float x) {
    x = fmaxf(x, dpp_f<DPP_QUAD_X1>(x));
    x = fmaxf(x, dpp_f<DPP_QUAD_X2>(x));
    return x;
}
__device__ __forceinline__ float quadsum4(float x) {
    x += dpp_f<DPP_QUAD_X1>(x);
    x += dpp_f<DPP_QUAD_X2>(x);
    return x;
}
__device__ __forceinline__ float wavemax(float x) {
    x = rowmax16(x);
    x = fmaxf(x, __shfl_xor(x, 16));
    x = fmaxf(x, __shfl_xor(x, 32));
    return x;
}
__device__ __forceinline__ float wavesum(float x) {
    x += dpp_f<DPP_ROR_1>(x); x += dpp_f<DPP_ROR_2>(x);
    x += dpp_f<DPP_ROR_4>(x); x += dpp_f<DPP_ROR_8>(x);
    x += __shfl_xor(x, 16);   x += __shfl_xor(x, 32);
    return x;
}
__device__ __forceinline__ float dot16(const float* __restrict__ qp, const float* kr) {
    float s = 0.f;
    #pragma unroll
    for (int i = 0; i < 4; ++i) {
        float4 a = *(const float4*)(qp + i*4);
        s = fmaf(a.x, kr[i*4+0], s);
        s = fmaf(a.y, kr[i*4+1], s);
        s = fmaf(a.z, kr[i*4+2], s);
        s = fmaf(a.w, kr[i*4+3], s);
    }
    return s;
}
__device__ __forceinline__ int child32(int s, int c) {
    return (((s >> 4)*2 + (c >> 1)) << 5) + ((s & 15)*2 + (c & 1));
}
__device__ __forceinline__ int child64(int g, int c) {
    return (((g >> 5)*2 + (c >> 1)) << 6) + ((g & 31)*2 + (c & 1));
}

// per-wave arena layout (floats)
#define W0V  560
#define W0P  576
#define MSG0 592
#define MSG1 608
#define W1V  672
#define W1P  704
#define GT   736
#define OUTT 864
#define ARENA 1120

// ---------------- Repack: head-major Q + KV-interleaved ----------------
__global__ __launch_bounds__(256) void k_repack(
    const float* __restrict__ q1, const float* __restrict__ k1, const float* __restrict__ v1,
    const float* __restrict__ q2, const float* __restrict__ k2, const float* __restrict__ v2,
    float* __restrict__ Q1h, float* __restrict__ KV1,
    float* __restrict__ Q2h, float* __restrict__ KV2)
{
    const int x = blockIdx.x, n = blockIdx.y, b = blockIdx.z;
    const int t = threadIdx.x;
    __shared__ float tA[16][129];
    __shared__ float tB[16][129];

    if (x < 20) {
        const float* src; float* dst; int S, ck;
        if (x < 4) { src = q1; dst = Q1h; S = 1024; ck = x; }
        else       { src = q2; dst = Q2h; S = 4096; ck = x - 4; }
        const int tok0 = ck * 256;
        const float* sp = src + ((size_t)(b*128 + n*16))*S + tok0;
        const int col = t & 127, half = t >> 7;
        #pragma unroll
        for (int j = 0; j < 8; ++j) {
            const int row = j*2 + half;
            tA[row][col] = sp[(size_t)row*S + col];
            tB[row][col] = sp[(size_t)row*S + col + 128];
        }
        __syncthreads();
        float* dp = dst + ((size_t)((b*8 + n)*S) + tok0 + t)*16;
        #pragma unroll
        for (int i = 0; i < 4; ++i) {
            float4 o;
            o.x = (half ? tB : tA)[i*4+0][col];
            o.y = (half ? tB : tA)[i*4+1][col];
            o.z = (half ? tB : tA)[i*4+2][col];
            o.w = (half ? tB : tA)[i*4+3][col];
            *(float4*)(dp + i*4) = o;
        }
    } else {
        const float* sK; const float* sV; float* dst; int S, ck;
        if (x < 28) { sK = k1; sV = v1; dst = KV1; S = 1024; ck = x - 20; }
        else        { sK = k2; sV = v2; dst = KV2; S = 4096; ck = x - 28; }
        const int tok0 = ck * 128;
        const int col = t & 127, rp = t >> 7;
        const float* kp = sK + ((size_t)(b*128 + n*16))*S + tok0;
        const float* vp = sV + ((size_t)(b*128 + n*16))*S + tok0;
        #pragma unroll
        for (int j = 0; j < 8; ++j) {
            const int row = j*2 + rp;
            tA[row][col] = kp[(size_t)row*S + col];
            tB[row][col] = vp[(size_t)row*S + col];
        }
        __syncthreads();
        const int tok = t >> 1, half = t & 1;
        float* dp = dst + (((size_t)((b*8 + n)*S) + tok0 + tok))*32 + half*16;
        #pragma unroll
        for (int i = 0; i < 4; ++i) {
            float4 o;
            o.x = (half ? tB : tA)[i*4+0][tok];
            o.y = (half ? tB : tA)[i*4+1][tok];
            o.z = (half ? tB : tA)[i*4+2][tok];
            o.w = (half ? tB : tA)[i*4+3][tok];
            *(float4*)(dp + i*4) = o;
        }
    }
}

// ---------------- Fused 3-level subtree kernel, 1 subtree/wave ---------
// grid (2048,1,1) x 256. id = (l0<<3) | (b<<1) | nh.
__global__ __launch_bounds__(256, 6) void k_fused(
    const float* __restrict__ q0, const float* __restrict__ k0, const float* __restrict__ v0,
    const float* __restrict__ Q1h, const float* __restrict__ KV1,
    const float* __restrict__ Q2h, const float* __restrict__ KV2,
    float* __restrict__ out)
{
    const int tid = threadIdx.x, lane = tid & 63, wid = tid >> 6;
    const int id = blockIdx.x;
    const int nh = id & 1;
    const int b  = (id >> 1) & 3;
    const int l0 = id >> 3;                  // 0..255
    const int n  = nh*4 + wid;
    const int H0 = l0 >> 4, W0 = l0 & 15;

    __shared__ float arenaAll[4][ARENA];
    float* const A = arenaAll[wid];

    const float* Q1hh = Q1h + (size_t)((b*8 + n)*1024)*16;
    const float* KV1h = KV1 + (size_t)((b*8 + n)*1024)*32;
    const float* Q2hh = Q2h + (size_t)((b*8 + n)*4096)*16;
    const float* KV2h = KV2 + (size_t)((b*8 + n)*4096)*32;

    // ======== stage A: lvl0 scores ========
    const float* qb = q0 + ((size_t)(b*128 + n*16))*256 + l0;
    const float* kb = k0 + ((size_t)(b*128 + n*16))*256 + lane*4;
    float qr[16];
    #pragma unroll
    for (int dd = 0; dd < 16; ++dd) qr[dd] = qb[(size_t)dd*256];
    float p[4] = {0.f,0.f,0.f,0.f};
    #pragma unroll
    for (int dd = 0; dd < 16; ++dd) {
        float4 kv = *(const float4*)(kb + (size_t)dd*256);
        p[0] = fmaf(qr[dd], kv.x, p[0]);
        p[1] = fmaf(qr[dd], kv.y, p[1]);
        p[2] = fmaf(qr[dd], kv.z, p[2]);
        p[3] = fmaf(qr[dd], kv.w, p[3]);
    }
    #pragma unroll
    for (int j = 0; j < 4; ++j) p[j] *= 0.25f;
    float mA = fmaxf(fmaxf(p[0], p[1]), fmaxf(p[2], p[3]));
    mA = wavemax(mA);
    float lsA = 0.f;
    #pragma unroll
    for (int j = 0; j < 4; ++j) { p[j] = expf(p[j] - mA); lsA += p[j]; }
    const float invA = 1.f / wavesum(lsA);
    #pragma unroll
    for (int j = 0; j < 4; ++j) p[j] *= invA;

    const int li = lane & 15;

    // ======== stage B: top-16 of 256 (per-row top-16, then rank merge) ====
    float w[4];
    #pragma unroll
    for (int j = 0; j < 4; ++j) w[j] = p[j];
    float cv = 0.f; int cpos = 0;
    #pragma unroll 1
    for (int it = 0; it < 16; ++it) {
        float bv = fmaxf(fmaxf(w[0], w[1]), fmaxf(w[2], w[3]));
        bv = rowmax16(bv);
        int cs = 0x7FFFFFFF;
        cs = (w[3] == bv) ? (lane*4 + 3) : cs;
        cs = (w[2] == bv) ? (lane*4 + 2) : cs;
        cs = (w[1] == bv) ? (lane*4 + 1) : cs;
        cs = (w[0] == bv) ? (lane*4 + 0) : cs;
        cs = rowmin16i(cs);
        w[0] = (cs == lane*4 + 0) ? 0.f : w[0];
        w[1] = (cs == lane*4 + 1) ? 0.f : w[1];
        w[2] = (cs == lane*4 + 2) ? 0.f : w[2];
        w[3] = (cs == lane*4 + 3) ? 0.f : w[3];
        if (li == it) { cv = bv; cpos = cs; }
    }
    // rank merge
    A[lane]      = cv;
    A[64 + lane] = __int_as_float(cpos);
    *(float4*)&A[288 + lane*4] = make_float4(0.f, 0.f, 0.f, 0.f);
    {
        const float cu = cv; const int pu = cpos;
        int rank = 0;
        #pragma unroll
        for (int jj = 0; jj < 16; ++jj) {
            float4 vv = *(const float4*)&A[jj*4];
            float4 pw = *(const float4*)&A[64 + jj*4];
            const int p0i = __float_as_int(pw.x), p1i = __float_as_int(pw.y);
            const int p2i = __float_as_int(pw.z), p3i = __float_as_int(pw.w);
            rank += (vv.x > cu || (vv.x == cu && p0i < pu)) ? 1 : 0;
            rank += (vv.y > cu || (vv.y == cu && p1i < pu)) ? 1 : 0;
            rank += (vv.z > cu || (vv.z == cu && p2i < pu)) ? 1 : 0;
            rank += (vv.w > cu || (vv.w == cu && p3i < pu)) ? 1 : 0;
        }
        if (rank < 16) {
            A[W0V + rank] = cu;
            A[W0P + rank] = __int_as_float(pu);
            A[288 + pu]   = 1.0f;
        }
    }
    {   // apply mask + padded store
        float4 fA = *(const float4*)&A[288 + lane*4];
        p[0] = (fA.x != 0.f) ? 0.f : p[0];
        p[1] = (fA.y != 0.f) ? 0.f : p[1];
        p[2] = (fA.z != 0.f) ? 0.f : p[2];
        p[3] = (fA.w != 0.f) ? 0.f : p[3];
        const int pad = lane*4 + 4*(lane>>4);
        *(float4*)&A[pad] = make_float4(p[0], p[1], p[2], p[3]);
    }

    // ======== early lvl1 child table + K prefetch ========
    float kr1[16];
    float psD;
    {
        const int kp = lane >> 2, ci = lane & 3;
        psD = A[W0V + kp];
        const int spos = __float_as_int(A[W0P + kp]);
        const int g1 = child32(spos, ci);
        A[GT + lane] = __int_as_float(g1);
        const float* kv = KV1h + (size_t)g1*32;
        #pragma unroll
        for (int i = 0; i < 4; ++i) *(float4*)&kr1[i*4] = *(const float4*)(kv + i*4);
    }

    // ======== stage C: msg0 ========
    {
        const int dd = lane & 15, chunk = lane >> 4;
        const float* vb = v0 + ((size_t)(b*128 + n*16 + dd))*256 + chunk*64;
        float a0 = 0.f;
        #pragma unroll
        for (int jj = 0; jj < 16; ++jj) {
            float4 vv = *(const float4*)(vb + jj*4);
            float4 p0 = *(const float4*)&A[chunk*68 + jj*4];
            a0 = fmaf(p0.x, vv.x, a0); a0 = fmaf(p0.y, vv.y, a0);
            a0 = fmaf(p0.z, vv.z, a0); a0 = fmaf(p0.w, vv.w, a0);
        }
        a0 += __shfl_xor(a0, 16); a0 += __shfl_xor(a0, 32);
        if (lane < 16) A[MSG0 + dd] = a0;
    }

    // ======== stage D: lvl1 scoring (kr1 preloaded) + top-8 ========
    #pragma unroll
    for (int t = 0; t < 4; ++t) {
        const int qtok = ((2*H0 + (t>>1)) << 5) + 2*W0 + (t&1);
        float sc = dot16(Q1hh + qtok*16, kr1) * 0.25f;
        const float mm = quadmax4(sc);
        const float e  = expf(sc - mm);
        const float su = quadsum4(e);
        A[288 + t*68 + lane] = (e / su) * psD;
    }
    {
        const int tg = lane >> 4;
        float r[4];
        {
            float4 t0 = *(const float4*)&A[288 + tg*68 + li*4];
            r[0] = t0.x; r[1] = t0.y; r[2] = t0.z; r[3] = t0.w;
        }
        float cv1 = 0.f; int cs1 = 0;
        #pragma unroll 1
        for (int it = 0; it < 8; ++it) {
            float bv = fmaxf(fmaxf(r[0], r[1]), fmaxf(r[2], r[3]));
            bv = rowmax16(bv);
            int cs = 0x7FFFFFFF;
            cs = (r[3] == bv) ? (li*4 + 3) : cs;
            cs = (r[2] == bv) ? (li*4 + 2) : cs;
            cs = (r[1] == bv) ? (li*4 + 1) : cs;
            cs = (r[0] == bv) ? (li*4 + 0) : cs;
            cs = rowmin16i(cs);
            r[0] = (cs == li*4 + 0) ? 0.f : r[0];
            r[1] = (cs == li*4 + 1) ? 0.f : r[1];
            r[2] = (cs == li*4 + 2) ? 0.f : r[2];
            r[3] = (cs == li*4 + 3) ? 0.f : r[3];
            if (li == it) { cv1 = bv; cs1 = cs; }
        }
        *(float4*)&A[288 + tg*68 + li*4] = make_float4(r[0], r[1], r[2], r[3]);
        if (li < 8) {
            A[W1V + tg*8 + li] = cv1;
            A[W1P + tg*8 + li] = A[GT + cs1];
        }
    }

    // ======== stage E: msg1 ========
    {
        const int ks = lane >> 4, t2 = (lane >> 2) & 3, dq = lane & 3;
        float4 acc = make_float4(0.f, 0.f, 0.f, 0.f);
        #pragma unroll
        for (int jj = 0; jj < 4; ++jj) {
            float4 pv = *(const float4*)&A[288 + t2*68 + ks*16 + jj*4];
            const float pa[4] = {pv.x, pv.y, pv.z, pv.w};
            #pragma unroll
            for (int c = 0; c < 4; ++c) {
                const int g = __float_as_int(A[GT + ks*16 + jj*4 + c]);
                float4 vv = *(const float4*)(KV1h + (size_t)g*32 + 16 + dq*4);
                acc.x = fmaf(pa[c], vv.x, acc.x);
                acc.y = fmaf(pa[c], vv.y, acc.y);
                acc.z = fmaf(pa[c], vv.z, acc.z);
                acc.w = fmaf(pa[c], vv.w, acc.w);
            }
        }
        acc.x += __shfl_xor(acc.x, 16); acc.y += __shfl_xor(acc.y, 16);
        acc.z += __shfl_xor(acc.z, 16); acc.w += __shfl_xor(acc.w, 16);
        acc.x += __shfl_xor(acc.x, 32); acc.y += __shfl_xor(acc.y, 32);
        acc.z += __shfl_xor(acc.z, 32); acc.w += __shfl_xor(acc.w, 32);
        if (lane < 16)
            *(float4*)&A[MSG1 + t2*16 + dq*4] = acc;
    }

    // ======== stage F: lvl2 ========
    {
        const int t1h = lane >> 5, kk = lane & 31;
        const int kp2 = kk >> 2, ci2 = kk & 3;
        float krA[16], krB[16];
        float psA, psB;
        // GT fill + all K loads up front (one wall)
        const int gA = child64(__float_as_int(A[W1P + t1h*8 + kp2]), ci2);
        const int gB = child64(__float_as_int(A[W1P + (2+t1h)*8 + kp2]), ci2);
        A[GT + t1h*32 + kk]     = __int_as_float(gA);
        A[GT + (2+t1h)*32 + kk] = __int_as_float(gB);
        psA = A[W1V + t1h*8 + kp2];
        psB = A[W1V + (2+t1h)*8 + kp2];
        const float* kva = KV2h + (size_t)gA*32;
        const float* kvb = KV2h + (size_t)gB*32;
        #pragma unroll
        for (int i = 0; i < 4; ++i) {
            *(float4*)&krA[i*4] = *(const float4*)(kva + i*4);
            *(float4*)&krB[i*4] = *(const float4*)(kvb + i*4);
        }
        // score pass 0 (t1 = t1h) and pass 1 (t1 = 2+t1h)
        {
            const int t1 = t1h;
            const int y1 = 2*H0 + (t1 >> 1), x1 = 2*W0 + (t1 & 1);
            #pragma unroll
            for (int t2 = 0; t2 < 4; ++t2) {
                const int qtok2 = ((2*y1 + (t2>>1)) << 6) + 2*x1 + (t2&1);
                float sc = dot16(Q2hh + qtok2*16, krA) * 0.25f;
                const float mm = quadmax4(sc);
                const float e  = expf(sc - mm);
                const float su = quadsum4(e);
                A[t1h*144 + t2*36 + kk] = (e / su) * psA;
            }
        }
        {
            const int t1 = 2 + t1h;
            const int y1 = 2*H0 + (t1 >> 1), x1 = 2*W0 + (t1 & 1);
            #pragma unroll
            for (int t2 = 0; t2 < 4; ++t2) {
                const int qtok2 = ((2*y1 + (t2>>1)) << 6) + 2*x1 + (t2&1);
                float sc = dot16(Q2hh + qtok2*16, krB) * 0.25f;
                const float mm = quadmax4(sc);
                const float e  = expf(sc - mm);
                const float su = quadsum4(e);
                A[288 + t1h*144 + t2*36 + kk] = (e / su) * psB;
            }
        }
    }
    // msg halves
    {
        const int ks2 = lane >> 5, qq = (lane >> 2) & 7, dq = lane & 3;
        const int t1l = qq >> 2, t2 = qq & 3;
        #pragma unroll
        for (int h = 0; h < 2; ++h) {
            const int t1 = h*2 + t1l;
            const int sb = (t1 >> 1)*288 + (t1 & 1)*144 + t2*36;
            float4 acc = make_float4(0.f, 0.f, 0.f, 0.f);
            #pragma unroll
            for (int j4 = 0; j4 < 4; ++j4) {
                float4 pv = *(const float4*)&A[sb + ks2*16 + j4*4];
                const float pa[4] = {pv.x, pv.y, pv.z, pv.w};
                #pragma unroll
                for (int c = 0; c < 4; ++c) {
                    const int g2 = __float_as_int(A[GT + t1*32 + ks2*16 + j4*4 + c]);
                    float4 vv = *(const float4*)(KV2h + (size_t)g2*32 + 16 + dq*4);
                    acc.x = fmaf(pa[c], vv.x, acc.x);
                    acc.y = fmaf(pa[c], vv.y, acc.y);
                    acc.z = fmaf(pa[c], vv.z, acc.z);
                    acc.w = fmaf(pa[c], vv.w, acc.w);
                }
            }
            acc.x += __shfl_xor(acc.x, 32); acc.y += __shfl_xor(acc.y, 32);
            acc.z += __shfl_xor(acc.z, 32); acc.w += __shfl_xor(acc.w, 32);
            if (lane < 32) {
                float4 m1 = *(const float4*)&A[MSG1 + t1*16 + dq*4];
                float4 m0 = *(const float4*)&A[MSG0 + dq*4];
                acc.x += m1.x + m0.x;
                acc.y += m1.y + m0.y;
                acc.z += m1.z + m0.z;
                acc.w += m1.w + m0.w;
                *(float4*)&A[OUTT + (t1*4 + t2)*16 + dq*4] = acc;
            }
        }
    }

    // ======== output: one 4x4 patch ========
    {
        const int y = lane & 3, dd = lane >> 2;
        float vr[4];
        #pragma unroll
        for (int x = 0; x < 4; ++x) {
            const int t1 = (((y>>1) << 1) | (x>>1));
            const int t2 = (((y&1)  << 1) | (x&1));
            vr[x] = A[OUTT + (t1*4 + t2)*16 + dd];
        }
        float* op = out + (((size_t)(b*128 + n*16 + dd)*64 + 4*H0 + y))*64 + 4*W0;
        *(float4*)op = make_float4(vr[0], vr[1], vr[2], vr[3]);
    }
}

extern "C" void kernel_launch(void* const* d_in, const int* in_sizes, int n_in,
                              void* d_out, int out_size, void* d_ws, size_t ws_size,
                              hipStream_t stream)
{
    const float* q0 = (const float*)d_in[0];
    const float* k0 = (const float*)d_in[1];
    const float* v0 = (const float*)d_in[2];
    const float* q1 = (const float*)d_in[3];
    const float* k1 = (const float*)d_in[4];
    const float* v1 = (const float*)d_in[5];
    const float* q2 = (const float*)d_in[6];
    const float* k2 = (const float*)d_in[7];
    const float* v2 = (const float*)d_in[8];

    float* ws  = (float*)d_ws;
    float* Q1h = ws;                 // 4*8*1024*16 = 524288
    float* KV1 = ws + 524288;        // 4*8*1024*32 = 1048576
    float* Q2h = ws + 1572864;       // 4*8*4096*16 = 2097152
    float* KV2 = ws + 3670016;       // 4*8*4096*32 = 4194304

    k_repack<<<dim3(60, 8, 4), 256, 0, stream>>>(q1, k1, v1, q2, k2, v2,
                                                 Q1h, KV1, Q2h, KV2);
    k_fused<<<dim3(2048, 1, 1), 256, 0, stream>>>(q0, k0, v0,
                                                  Q1h, KV1, Q2h, KV2,
                                                  (float*)d_out);
}

// Round 3
// 157.313 us; speedup vs baseline: 1.0876x; 1.0721x over previous
//
#include <hip/hip_runtime.h>
#include <cstddef>

// QuadTree attention, 3 levels. B=4, C=128, NHEAD=8, d=16.
// Grids: 16x16 (S=256), 32x32 (S=1024), 64x64 (S=4096). TOPKS=(16,8,8).
//
// R12: R9 paired structure (2 subtrees/wave, shared lvl0 K/V tile loads,
// 32B-contiguous output rows) + arena compaction 1120 -> 796 floats/context:
//   - OUTT relocated to [0..256), overlapping the stage-F score region
//     (dead after msg-half reads; accs held in regs, stores deferred).
//   - GT[64..128) aliased onto W1V/W1P (dead at stage-F header; reads
//     reordered before GT writes; per-wave LDS ops are in-order).
//   - W0V/W0P packed at 556/572 (dead before stage-F scores reach 571).
// LDS 35840 -> 25472 B/block: 4 -> 6 blocks/CU (16 -> 24 waves/CU cap).
// launch_bounds stays (256,4): R10/R11 showed tighter bounds make the
// allocator clamp+spill; actual VGPR=64 already permits 6 waves/SIMD.
// XCD swizzle id&7=(b<<1)|nh keeps per-XCD KV working set in XCD L2.

#define DPP_QUAD_X1 0xB1
#define DPP_QUAD_X2 0x4E
#define DPP_ROR_1   0x121
#define DPP_ROR_2   0x122
#define DPP_ROR_4   0x124
#define DPP_ROR_8   0x128

template<int C>
__device__ __forceinline__ int dpp_i(int x) {
    return __builtin_amdgcn_mov_dpp(x, C, 0xF, 0xF, true);
}
template<int C>
__device__ __forceinline__ float dpp_f(float x) {
    return __int_as_float(__builtin_amdgcn_mov_dpp(__float_as_int(x), C, 0xF, 0xF, true));
}
__device__ __forceinline__ float rowmax16(float x) {
    x = fmaxf(x, dpp_f<DPP_ROR_1>(x));
    x = fmaxf(x, dpp_f<DPP_ROR_2>(x));
    x = fmaxf(x, dpp_f<DPP_ROR_4>(x));
    x = fmaxf(x, dpp_f<DPP_ROR_8>(x));
    return x;
}
__device__ __forceinline__ int rowmin16i(int x) {
    { int o = dpp_i<DPP_ROR_1>(x); x = o < x ? o : x; }
    { int o = dpp_i<DPP_ROR_2>(x); x = o < x ? o : x; }
    { int o = dpp_i<DPP_ROR_4>(x); x = o < x ? o : x; }
    { int o = dpp_i<DPP_ROR_8>(x); x = o < x ? o : x; }
    return x;
}
__device__ __forceinline__ float quadmax4(float x) {
    x = fmaxf(x, dpp_f<DPP_QUAD_X1>(x));
    x = fmaxf(x, dpp_f<DPP_QUAD_X2>(x));
    return x;
}
__device__ __forceinline__ float quadsum4(float x) {
    x += dpp_f<DPP_QUAD_X1>(x);
    x += dpp_f<DPP_QUAD_X2>(x);
    return x;
}
__device__ __forceinline__ float wavemax(float x) {
    x = rowmax16(x);
    x = fmaxf(x, __shfl_xor(x, 16));
    x = fmaxf(x, __shfl_xor(x, 32));
    return x;
}
__device__ __forceinline__ float wavesum(float x) {
    x += dpp_f<DPP_ROR_1>(x); x += dpp_f<DPP_ROR_2>(x);
    x += dpp_f<DPP_ROR_4>(x); x += dpp_f<DPP_ROR_8>(x);
    x += __shfl_xor(x, 16);   x += __shfl_xor(x, 32);
    return x;
}
__device__ __forceinline__ float dot16(const float* __restrict__ qp, const float* kr) {
    float s = 0.f;
    #pragma unroll
    for (int i = 0; i < 4; ++i) {
        float4 a = *(const float4*)(qp + i*4);
        s = fmaf(a.x, kr[i*4+0], s);
        s = fmaf(a.y, kr[i*4+1], s);
        s = fmaf(a.z, kr[i*4+2], s);
        s = fmaf(a.w, kr[i*4+3], s);
    }
    return s;
}
__device__ __forceinline__ int child32(int s, int c) {
    return (((s >> 4)*2 + (c >> 1)) << 5) + ((s & 15)*2 + (c & 1));
}
__device__ __forceinline__ int child64(int g, int c) {
    return (((g >> 5)*2 + (c >> 1)) << 6) + ((g & 31)*2 + (c & 1));
}

// per-context arena layout (floats), 796 total:
//   [0..572)   scores (stage A/B pad+flags, stage D at +288, stage F both)
//   OUTT = 0   output staging, written only after all score reads (stage F)
//   [556..572) W0V  (dead before stage-F scores overwrite)
//   [572..588) W0P
//   [588..604) MSG0
//   [604..668) MSG1
//   [668..700) W1V  \ aliased by GT2 = GT entries [64..128) in stage F
//   [700..732) W1P  /
//   [732..796) GT   = GT entries [0..64)
#define OUTT 0
#define W0V  556
#define W0P  572
#define MSG0 588
#define MSG1 604
#define W1V  668
#define W1P  700
#define GT2  668
#define GT   732
#define ARENA 796

// ---------------- Repack: head-major Q + KV-interleaved ----------------
__global__ __launch_bounds__(256) void k_repack(
    const float* __restrict__ q1, const float* __restrict__ k1, const float* __restrict__ v1,
    const float* __restrict__ q2, const float* __restrict__ k2, const float* __restrict__ v2,
    float* __restrict__ Q1h, float* __restrict__ KV1,
    float* __restrict__ Q2h, float* __restrict__ KV2)
{
    const int x = blockIdx.x, n = blockIdx.y, b = blockIdx.z;
    const int t = threadIdx.x;
    __shared__ float tA[16][129];
    __shared__ float tB[16][129];

    if (x < 20) {
        const float* src; float* dst; int S, ck;
        if (x < 4) { src = q1; dst = Q1h; S = 1024; ck = x; }
        else       { src = q2; dst = Q2h; S = 4096; ck = x - 4; }
        const int tok0 = ck * 256;
        const float* sp = src + ((size_t)(b*128 + n*16))*S + tok0;
        const int col = t & 127, half = t >> 7;
        #pragma unroll
        for (int j = 0; j < 8; ++j) {
            const int row = j*2 + half;
            tA[row][col] = sp[(size_t)row*S + col];
            tB[row][col] = sp[(size_t)row*S + col + 128];
        }
        __syncthreads();
        float* dp = dst + ((size_t)((b*8 + n)*S) + tok0 + t)*16;
        #pragma unroll
        for (int i = 0; i < 4; ++i) {
            float4 o;
            o.x = (half ? tB : tA)[i*4+0][col];
            o.y = (half ? tB : tA)[i*4+1][col];
            o.z = (half ? tB : tA)[i*4+2][col];
            o.w = (half ? tB : tA)[i*4+3][col];
            *(float4*)(dp + i*4) = o;
        }
    } else {
        const float* sK; const float* sV; float* dst; int S, ck;
        if (x < 28) { sK = k1; sV = v1; dst = KV1; S = 1024; ck = x - 20; }
        else        { sK = k2; sV = v2; dst = KV2; S = 4096; ck = x - 28; }
        const int tok0 = ck * 128;
        const int col = t & 127, rp = t >> 7;
        const float* kp = sK + ((size_t)(b*128 + n*16))*S + tok0;
        const float* vp = sV + ((size_t)(b*128 + n*16))*S + tok0;
        #pragma unroll
        for (int j = 0; j < 8; ++j) {
            const int row = j*2 + rp;
            tA[row][col] = kp[(size_t)row*S + col];
            tB[row][col] = vp[(size_t)row*S + col];
        }
        __syncthreads();
        const int tok = t >> 1, half = t & 1;
        float* dp = dst + (((size_t)((b*8 + n)*S) + tok0 + tok))*32 + half*16;
        #pragma unroll
        for (int i = 0; i < 4; ++i) {
            float4 o;
            o.x = (half ? tB : tA)[i*4+0][tok];
            o.y = (half ? tB : tA)[i*4+1][tok];
            o.z = (half ? tB : tA)[i*4+2][tok];
            o.w = (half ? tB : tA)[i*4+3][tok];
            *(float4*)(dp + i*4) = o;
        }
    }
}

// ---------------- Fused 3-level subtree kernel, 2 subtrees/wave ---------
// grid (1024,1,1) x 256. id = (lpair<<3) | (b<<1) | nh.
__global__ __launch_bounds__(256, 4) void k_fused(
    const float* __restrict__ q0, const float* __restrict__ k0, const float* __restrict__ v0,
    const float* __restrict__ Q1h, const float* __restrict__ KV1,
    const float* __restrict__ Q2h, const float* __restrict__ KV2,
    float* __restrict__ out)
{
    const int tid = threadIdx.x, lane = tid & 63, wid = tid >> 6;
    const int id    = blockIdx.x;
    const int nh    = id & 1;
    const int b     = (id >> 1) & 3;
    const int lpair = id >> 3;               // 0..127
    const int n     = nh*4 + wid;
    const int l0b   = lpair*2;               // even
    const int H0 = l0b >> 4, W0b = l0b & 15; // both contexts share H0; W0u=W0b+u

    __shared__ float arenaAll[4][2][ARENA];
    float* const A0 = arenaAll[wid][0];
    float* const A1 = arenaAll[wid][1];

    const float* Q1hh = Q1h + (size_t)((b*8 + n)*1024)*16;
    const float* KV1h = KV1 + (size_t)((b*8 + n)*1024)*32;
    const float* Q2hh = Q2h + (size_t)((b*8 + n)*4096)*16;
    const float* KV2h = KV2 + (size_t)((b*8 + n)*4096)*32;

    // ======== stage A: lvl0 scores, K shared, q as float2 ========
    const float* qb = q0 + ((size_t)(b*128 + n*16))*256 + l0b;
    const float* kb = k0 + ((size_t)(b*128 + n*16))*256 + lane*4;
    float2 q2r[16];
    #pragma unroll
    for (int dd = 0; dd < 16; ++dd) q2r[dd] = *(const float2*)(qb + (size_t)dd*256);
    float pA[4] = {0.f,0.f,0.f,0.f}, pB[4] = {0.f,0.f,0.f,0.f};
    #pragma unroll
    for (int dd = 0; dd < 16; ++dd) {
        float4 kv = *(const float4*)(kb + (size_t)dd*256);
        pA[0] = fmaf(q2r[dd].x, kv.x, pA[0]);
        pA[1] = fmaf(q2r[dd].x, kv.y, pA[1]);
        pA[2] = fmaf(q2r[dd].x, kv.z, pA[2]);
        pA[3] = fmaf(q2r[dd].x, kv.w, pA[3]);
        pB[0] = fmaf(q2r[dd].y, kv.x, pB[0]);
        pB[1] = fmaf(q2r[dd].y, kv.y, pB[1]);
        pB[2] = fmaf(q2r[dd].y, kv.z, pB[2]);
        pB[3] = fmaf(q2r[dd].y, kv.w, pB[3]);
    }
    #pragma unroll
    for (int j = 0; j < 4; ++j) { pA[j] *= 0.25f; pB[j] *= 0.25f; }
    float mA = fmaxf(fmaxf(pA[0], pA[1]), fmaxf(pA[2], pA[3]));
    float mB = fmaxf(fmaxf(pB[0], pB[1]), fmaxf(pB[2], pB[3]));
    mA = wavemax(mA); mB = wavemax(mB);
    float lsA = 0.f, lsB = 0.f;
    #pragma unroll
    for (int j = 0; j < 4; ++j) {
        pA[j] = expf(pA[j] - mA); lsA += pA[j];
        pB[j] = expf(pB[j] - mB); lsB += pB[j];
    }
    const float invA = 1.f / wavesum(lsA);
    const float invB = 1.f / wavesum(lsB);
    #pragma unroll
    for (int j = 0; j < 4; ++j) { pA[j] *= invA; pB[j] *= invB; }

    const int li = lane & 15;

    // ======== stage B: top-16 of 256, both contexts interleaved ========
    float w[2][4];
    #pragma unroll
    for (int j = 0; j < 4; ++j) { w[0][j] = pA[j]; w[1][j] = pB[j]; }
    float cv[2] = {0.f, 0.f}; int cpos[2] = {0, 0};
    #pragma unroll 1
    for (int it = 0; it < 16; ++it) {
        #pragma unroll
        for (int u = 0; u < 2; ++u) {
            float bv = fmaxf(fmaxf(w[u][0], w[u][1]), fmaxf(w[u][2], w[u][3]));
            bv = rowmax16(bv);
            int cs = 0x7FFFFFFF;
            cs = (w[u][3] == bv) ? (lane*4 + 3) : cs;
            cs = (w[u][2] == bv) ? (lane*4 + 2) : cs;
            cs = (w[u][1] == bv) ? (lane*4 + 1) : cs;
            cs = (w[u][0] == bv) ? (lane*4 + 0) : cs;
            cs = rowmin16i(cs);
            w[u][0] = (cs == lane*4 + 0) ? 0.f : w[u][0];
            w[u][1] = (cs == lane*4 + 1) ? 0.f : w[u][1];
            w[u][2] = (cs == lane*4 + 2) ? 0.f : w[u][2];
            w[u][3] = (cs == lane*4 + 3) ? 0.f : w[u][3];
            if (li == it) { cv[u] = bv; cpos[u] = cs; }
        }
    }
    // rank merge per context
    #pragma unroll
    for (int u = 0; u < 2; ++u) {
        float* A = u ? A1 : A0;
        A[lane]      = cv[u];
        A[64 + lane] = __int_as_float(cpos[u]);
        *(float4*)&A[288 + lane*4] = make_float4(0.f, 0.f, 0.f, 0.f);
    }
    #pragma unroll
    for (int u = 0; u < 2; ++u) {
        float* A = u ? A1 : A0;
        const float cu = cv[u]; const int pu = cpos[u];
        int rank = 0;
        #pragma unroll
        for (int jj = 0; jj < 16; ++jj) {
            float4 vv = *(const float4*)&A[jj*4];
            float4 pw = *(const float4*)&A[64 + jj*4];
            const int p0i = __float_as_int(pw.x), p1i = __float_as_int(pw.y);
            const int p2i = __float_as_int(pw.z), p3i = __float_as_int(pw.w);
            rank += (vv.x > cu || (vv.x == cu && p0i < pu)) ? 1 : 0;
            rank += (vv.y > cu || (vv.y == cu && p1i < pu)) ? 1 : 0;
            rank += (vv.z > cu || (vv.z == cu && p2i < pu)) ? 1 : 0;
            rank += (vv.w > cu || (vv.w == cu && p3i < pu)) ? 1 : 0;
        }
        if (rank < 16) {
            A[W0V + rank] = cu;
            A[W0P + rank] = __int_as_float(pu);
            A[288 + pu]   = 1.0f;
        }
    }
    {   // apply masks + padded store
        float4 fA = *(const float4*)&A0[288 + lane*4];
        float4 fB = *(const float4*)&A1[288 + lane*4];
        pA[0] = (fA.x != 0.f) ? 0.f : pA[0];
        pA[1] = (fA.y != 0.f) ? 0.f : pA[1];
        pA[2] = (fA.z != 0.f) ? 0.f : pA[2];
        pA[3] = (fA.w != 0.f) ? 0.f : pA[3];
        pB[0] = (fB.x != 0.f) ? 0.f : pB[0];
        pB[1] = (fB.y != 0.f) ? 0.f : pB[1];
        pB[2] = (fB.z != 0.f) ? 0.f : pB[2];
        pB[3] = (fB.w != 0.f) ? 0.f : pB[3];
        const int pad = lane*4 + 4*(lane>>4);
        *(float4*)&A0[pad] = make_float4(pA[0], pA[1], pA[2], pA[3]);
        *(float4*)&A1[pad] = make_float4(pB[0], pB[1], pB[2], pB[3]);
    }

    // ======== early lvl1 child table + K prefetch (both contexts) ========
    float kr1[2][16];
    float psD[2];
    {
        const int kp = lane >> 2, ci = lane & 3;
        #pragma unroll
        for (int u = 0; u < 2; ++u) {
            float* A = u ? A1 : A0;
            psD[u] = A[W0V + kp];
            const int spos = __float_as_int(A[W0P + kp]);
            const int g1 = child32(spos, ci);
            A[GT + lane] = __int_as_float(g1);
            const float* kv = KV1h + (size_t)g1*32;
            #pragma unroll
            for (int i = 0; i < 4; ++i) *(float4*)&kr1[u][i*4] = *(const float4*)(kv + i*4);
        }
    }

    // ======== stage C: msg0, V loads shared across contexts ========
    {
        const int dd = lane & 15, chunk = lane >> 4;
        const float* vb = v0 + ((size_t)(b*128 + n*16 + dd))*256 + chunk*64;
        float a0 = 0.f, a1 = 0.f;
        #pragma unroll
        for (int jj = 0; jj < 16; ++jj) {
            float4 vv = *(const float4*)(vb + jj*4);
            float4 p0 = *(const float4*)&A0[chunk*68 + jj*4];
            float4 p1 = *(const float4*)&A1[chunk*68 + jj*4];
            a0 = fmaf(p0.x, vv.x, a0); a0 = fmaf(p0.y, vv.y, a0);
            a0 = fmaf(p0.z, vv.z, a0); a0 = fmaf(p0.w, vv.w, a0);
            a1 = fmaf(p1.x, vv.x, a1); a1 = fmaf(p1.y, vv.y, a1);
            a1 = fmaf(p1.z, vv.z, a1); a1 = fmaf(p1.w, vv.w, a1);
        }
        a0 += __shfl_xor(a0, 16); a0 += __shfl_xor(a0, 32);
        a1 += __shfl_xor(a1, 16); a1 += __shfl_xor(a1, 32);
        if (lane < 16) { A0[MSG0 + dd] = a0; A1[MSG0 + dd] = a1; }
    }

    // ======== stage D: lvl1 scoring (kr1 preloaded) + top-8 ========
    #pragma unroll
    for (int u = 0; u < 2; ++u) {
        float* A = u ? A1 : A0;
        const int W0u = W0b + u;
        #pragma unroll
        for (int t = 0; t < 4; ++t) {
            const int qtok = ((2*H0 + (t>>1)) << 5) + 2*W0u + (t&1);
            float sc = dot16(Q1hh + qtok*16, kr1[u]) * 0.25f;
            const float mm = quadmax4(sc);
            const float e  = expf(sc - mm);
            const float su = quadsum4(e);
            A[288 + t*68 + lane] = (e / su) * psD[u];
        }
    }
    {
        const int tg = lane >> 4;
        float r[2][4];
        {
            float4 t0 = *(const float4*)&A0[288 + tg*68 + li*4];
            float4 t1 = *(const float4*)&A1[288 + tg*68 + li*4];
            r[0][0] = t0.x; r[0][1] = t0.y; r[0][2] = t0.z; r[0][3] = t0.w;
            r[1][0] = t1.x; r[1][1] = t1.y; r[1][2] = t1.z; r[1][3] = t1.w;
        }
        float cv1[2] = {0.f, 0.f}; int cs1[2] = {0, 0};
        #pragma unroll 1
        for (int it = 0; it < 8; ++it) {
            #pragma unroll
            for (int u = 0; u < 2; ++u) {
                float bv = fmaxf(fmaxf(r[u][0], r[u][1]), fmaxf(r[u][2], r[u][3]));
                bv = rowmax16(bv);
                int cs = 0x7FFFFFFF;
                cs = (r[u][3] == bv) ? (li*4 + 3) : cs;
                cs = (r[u][2] == bv) ? (li*4 + 2) : cs;
                cs = (r[u][1] == bv) ? (li*4 + 1) : cs;
                cs = (r[u][0] == bv) ? (li*4 + 0) : cs;
                cs = rowmin16i(cs);
                r[u][0] = (cs == li*4 + 0) ? 0.f : r[u][0];
                r[u][1] = (cs == li*4 + 1) ? 0.f : r[u][1];
                r[u][2] = (cs == li*4 + 2) ? 0.f : r[u][2];
                r[u][3] = (cs == li*4 + 3) ? 0.f : r[u][3];
                if (li == it) { cv1[u] = bv; cs1[u] = cs; }
            }
        }
        #pragma unroll
        for (int u = 0; u < 2; ++u) {
            float* A = u ? A1 : A0;
            *(float4*)&A[288 + tg*68 + li*4] =
                make_float4(r[u][0], r[u][1], r[u][2], r[u][3]);
            if (li < 8) {
                A[W1V + tg*8 + li] = cv1[u];
                A[W1P + tg*8 + li] = A[GT + cs1[u]];
            }
        }
    }

    // ======== stage E: msg1 per context ========
    {
        const int ks = lane >> 4, t2 = (lane >> 2) & 3, dq = lane & 3;
        #pragma unroll
        for (int u = 0; u < 2; ++u) {
            float* A = u ? A1 : A0;
            float4 acc = make_float4(0.f, 0.f, 0.f, 0.f);
            #pragma unroll
            for (int jj = 0; jj < 4; ++jj) {
                float4 pv = *(const float4*)&A[288 + t2*68 + ks*16 + jj*4];
                const float pa[4] = {pv.x, pv.y, pv.z, pv.w};
                #pragma unroll
                for (int c = 0; c < 4; ++c) {
                    const int g = __float_as_int(A[GT + ks*16 + jj*4 + c]);
                    float4 vv = *(const float4*)(KV1h + (size_t)g*32 + 16 + dq*4);
                    acc.x = fmaf(pa[c], vv.x, acc.x);
                    acc.y = fmaf(pa[c], vv.y, acc.y);
                    acc.z = fmaf(pa[c], vv.z, acc.z);
                    acc.w = fmaf(pa[c], vv.w, acc.w);
                }
            }
            acc.x += __shfl_xor(acc.x, 16); acc.y += __shfl_xor(acc.y, 16);
            acc.z += __shfl_xor(acc.z, 16); acc.w += __shfl_xor(acc.w, 16);
            acc.x += __shfl_xor(acc.x, 32); acc.y += __shfl_xor(acc.y, 32);
            acc.z += __shfl_xor(acc.z, 32); acc.w += __shfl_xor(acc.w, 32);
            if (lane < 16)
                *(float4*)&A[MSG1 + t2*16 + dq*4] = acc;
        }
    }

    // ======== stage F: lvl2 ========
    {
        const int t1h = lane >> 5, kk = lane & 31;
        const int kp2 = kk >> 2, ci2 = kk & 3;
        float krA[2][16], krB[2][16];
        float psA[2], psB[2];
        // GT fill + all K loads up front (one wall).
        // NOTE: GT2 aliases W1V/W1P — all W1V/W1P reads MUST precede the
        // GT writes (per-wave LDS ops execute in program order).
        #pragma unroll
        for (int u = 0; u < 2; ++u) {
            float* A = u ? A1 : A0;
            const int wpA = __float_as_int(A[W1P + t1h*8 + kp2]);
            const int wpB = __float_as_int(A[W1P + (2+t1h)*8 + kp2]);
            psA[u] = A[W1V + t1h*8 + kp2];
            psB[u] = A[W1V + (2+t1h)*8 + kp2];
            const int gA = child64(wpA, ci2);
            const int gB = child64(wpB, ci2);
            A[GT  + t1h*32 + kk] = __int_as_float(gA);   // GT idx [0..64)
            A[GT2 + t1h*32 + kk] = __int_as_float(gB);   // GT idx [64..128)
            const float* kva = KV2h + (size_t)gA*32;
            const float* kvb = KV2h + (size_t)gB*32;
            #pragma unroll
            for (int i = 0; i < 4; ++i) {
                *(float4*)&krA[u][i*4] = *(const float4*)(kva + i*4);
                *(float4*)&krB[u][i*4] = *(const float4*)(kvb + i*4);
            }
        }
        // score pass 0 (t1 = t1h) and pass 1 (t1 = 2+t1h) per context
        #pragma unroll
        for (int u = 0; u < 2; ++u) {
            float* A = u ? A1 : A0;
            const int W0u = W0b + u;
            {
                const int t1 = t1h;
                const int y1 = 2*H0 + (t1 >> 1), x1 = 2*W0u + (t1 & 1);
                #pragma unroll
                for (int t2 = 0; t2 < 4; ++t2) {
                    const int qtok2 = ((2*y1 + (t2>>1)) << 6) + 2*x1 + (t2&1);
                    float sc = dot16(Q2hh + qtok2*16, krA[u]) * 0.25f;
                    const float mm = quadmax4(sc);
                    const float e  = expf(sc - mm);
                    const float su = quadsum4(e);
                    A[t1h*144 + t2*36 + kk] = (e / su) * psA[u];
                }
            }
            {
                const int t1 = 2 + t1h;
                const int y1 = 2*H0 + (t1 >> 1), x1 = 2*W0u + (t1 & 1);
                #pragma unroll
                for (int t2 = 0; t2 < 4; ++t2) {
                    const int qtok2 = ((2*y1 + (t2>>1)) << 6) + 2*x1 + (t2&1);
                    float sc = dot16(Q2hh + qtok2*16, krB[u]) * 0.25f;
                    const float mm = quadmax4(sc);
                    const float e  = expf(sc - mm);
                    const float su = quadsum4(e);
                    A[288 + t1h*144 + t2*36 + kk] = (e / su) * psB[u];
                }
            }
        }
    }
    // msg halves per context. OUTT overlaps the score region, so both
    // h-accumulators are finished in registers before any OUTT store.
    {
        const int ks2 = lane >> 5, qq = (lane >> 2) & 7, dq = lane & 3;
        const int t1l = qq >> 2, t2 = qq & 3;
        #pragma unroll
        for (int u = 0; u < 2; ++u) {
            float* A = u ? A1 : A0;
            float4 accs[2];
            #pragma unroll
            for (int h = 0; h < 2; ++h) {
                const int t1 = h*2 + t1l;
                const int sb = (t1 >> 1)*288 + (t1 & 1)*144 + t2*36;
                const int gtb = (h == 0) ? GT : GT2;   // GT idx [0..64) / [64..128)
                float4 acc = make_float4(0.f, 0.f, 0.f, 0.f);
                #pragma unroll
                for (int j4 = 0; j4 < 4; ++j4) {
                    float4 pv = *(const float4*)&A[sb + ks2*16 + j4*4];
                    const float pa[4] = {pv.x, pv.y, pv.z, pv.w};
                    #pragma unroll
                    for (int c = 0; c < 4; ++c) {
                        const int g2 = __float_as_int(A[gtb + t1l*32 + ks2*16 + j4*4 + c]);
                        float4 vv = *(const float4*)(KV2h + (size_t)g2*32 + 16 + dq*4);
                        acc.x = fmaf(pa[c], vv.x, acc.x);
                        acc.y = fmaf(pa[c], vv.y, acc.y);
                        acc.z = fmaf(pa[c], vv.z, acc.z);
                        acc.w = fmaf(pa[c], vv.w, acc.w);
                    }
                }
                acc.x += __shfl_xor(acc.x, 32); acc.y += __shfl_xor(acc.y, 32);
                acc.z += __shfl_xor(acc.z, 32); acc.w += __shfl_xor(acc.w, 32);
                float4 m1 = *(const float4*)&A[MSG1 + t1*16 + dq*4];
                float4 m0 = *(const float4*)&A[MSG0 + dq*4];
                acc.x += m1.x + m0.x;
                acc.y += m1.y + m0.y;
                acc.z += m1.z + m0.z;
                acc.w += m1.w + m0.w;
                accs[h] = acc;
            }
            if (lane < 32) {
                *(float4*)&A[OUTT + ((t1l    )*4 + t2)*16 + dq*4] = accs[0];
                *(float4*)&A[OUTT + ((2 + t1l)*4 + t2)*16 + dq*4] = accs[1];
            }
        }
    }

    // ======== output: two adjacent 4x4 patches (same rows) ========
    {
        const int y = lane & 3, dd = lane >> 2;
        #pragma unroll
        for (int u = 0; u < 2; ++u) {
            float* A = u ? A1 : A0;
            const int W0u = W0b + u;
            float vr[4];
            #pragma unroll
            for (int x = 0; x < 4; ++x) {
                const int t1 = (((y>>1) << 1) | (x>>1));
                const int t2 = (((y&1)  << 1) | (x&1));
                vr[x] = A[OUTT + (t1*4 + t2)*16 + dd];
            }
            float* op = out + (((size_t)(b*128 + n*16 + dd)*64 + 4*H0 + y))*64 + 4*W0u;
            *(float4*)op = make_float4(vr[0], vr[1], vr[2], vr[3]);
        }
    }
}

extern "C" void kernel_launch(void* const* d_in, const int* in_sizes, int n_in,
                              void* d_out, int out_size, void* d_ws, size_t ws_size,
                              hipStream_t stream)
{
    const float* q0 = (const float*)d_in[0];
    const float* k0 = (const float*)d_in[1];
    const float* v0 = (const float*)d_in[2];
    const float* q1 = (const float*)d_in[3];
    const float* k1 = (const float*)d_in[4];
    const float* v1 = (const float*)d_in[5];
    const float* q2 = (const float*)d_in[6];
    const float* k2 = (const float*)d_in[7];
    const float* v2 = (const float*)d_in[8];

    float* ws  = (float*)d_ws;
    float* Q1h = ws;                 // 4*8*1024*16 = 524288
    float* KV1 = ws + 524288;        // 4*8*1024*32 = 1048576
    float* Q2h = ws + 1572864;       // 4*8*4096*16 = 2097152
    float* KV2 = ws + 3670016;       // 4*8*4096*32 = 4194304

    k_repack<<<dim3(60, 8, 4), 256, 0, stream>>>(q1, k1, v1, q2, k2, v2,
                                                 Q1h, KV1, Q2h, KV2);
    k_fused<<<dim3(1024, 1, 1), 256, 0, stream>>>(q0, k0, v0,
                                                  Q1h, KV1, Q2h, KV2,
                                                  (float*)d_out);
}

// Round 4
// 152.894 us; speedup vs baseline: 1.1190x; 1.0289x over previous
//
#include <hip/hip_runtime.h>
#include <cstddef>

// QuadTree attention, 3 levels. B=4, C=128, NHEAD=8, d=16.
// Grids: 16x16 (S=256), 32x32 (S=1024), 64x64 (S=4096). TOPKS=(16,8,8).
//
// R13: R12 paired structure + compact arena, with stage B's top-16-of-256
// rewritten as a bit-pattern bisection threshold search:
//   - count(p > t) via 4x v_cmp+__ballot (VALU) + SALU popcount/adds;
//     early-exit when count==16. No DPP reduction chains, no rank merge,
//     no flag array. Winners compacted to W0V/W0P via ballot+mbcnt prefix
//     (unsorted: downstream only uses value-pos pairs). Mask applied
//     directly: p = (p > t*) ? 0 : p.
//   - Selection set identical to iterative extraction for distinct values;
//     16/17-boundary ties (prob ~0) degrade to lowest-index via rank cap,
//     matching jax.lax.top_k tie-break.
// Rationale: R9-R12 all show VALUBusy*dur ~= 33us-equiv and occupancy is
// grid-capped (1024 blocks / 256 CU = 4 blk/CU; total 4096 waves = 16/CU).
// Stage B was ~1/3 of VALU slots and the longest serial chain -> cut it.
// XCD swizzle id&7=(b<<1)|nh keeps per-XCD KV working set in XCD L2.

#define DPP_QUAD_X1 0xB1
#define DPP_QUAD_X2 0x4E
#define DPP_ROR_1   0x121
#define DPP_ROR_2   0x122
#define DPP_ROR_4   0x124
#define DPP_ROR_8   0x128

template<int C>
__device__ __forceinline__ int dpp_i(int x) {
    return __builtin_amdgcn_mov_dpp(x, C, 0xF, 0xF, true);
}
template<int C>
__device__ __forceinline__ float dpp_f(float x) {
    return __int_as_float(__builtin_amdgcn_mov_dpp(__float_as_int(x), C, 0xF, 0xF, true));
}
__device__ __forceinline__ float rowmax16(float x) {
    x = fmaxf(x, dpp_f<DPP_ROR_1>(x));
    x = fmaxf(x, dpp_f<DPP_ROR_2>(x));
    x = fmaxf(x, dpp_f<DPP_ROR_4>(x));
    x = fmaxf(x, dpp_f<DPP_ROR_8>(x));
    return x;
}
__device__ __forceinline__ int rowmin16i(int x) {
    { int o = dpp_i<DPP_ROR_1>(x); x = o < x ? o : x; }
    { int o = dpp_i<DPP_ROR_2>(x); x = o < x ? o : x; }
    { int o = dpp_i<DPP_ROR_4>(x); x = o < x ? o : x; }
    { int o = dpp_i<DPP_ROR_8>(x); x = o < x ? o : x; }
    return x;
}
__device__ __forceinline__ float quadmax4(float x) {
    x = fmaxf(x, dpp_f<DPP_QUAD_X1>(x));
    x = fmaxf(x, dpp_f<DPP_QUAD_X2>(x));
    return x;
}
__device__ __forceinline__ float quadsum4(float x) {
    x += dpp_f<DPP_QUAD_X1>(x);
    x += dpp_f<DPP_QUAD_X2>(x);
    return x;
}
__device__ __forceinline__ float wavemax(float x) {
    x = rowmax16(x);
    x = fmaxf(x, __shfl_xor(x, 16));
    x = fmaxf(x, __shfl_xor(x, 32));
    return x;
}
__device__ __forceinline__ float wavesum(float x) {
    x += dpp_f<DPP_ROR_1>(x); x += dpp_f<DPP_ROR_2>(x);
    x += dpp_f<DPP_ROR_4>(x); x += dpp_f<DPP_ROR_8>(x);
    x += __shfl_xor(x, 16);   x += __shfl_xor(x, 32);
    return x;
}
__device__ __forceinline__ float dot16(const float* __restrict__ qp, const float* kr) {
    float s = 0.f;
    #pragma unroll
    for (int i = 0; i < 4; ++i) {
        float4 a = *(const float4*)(qp + i*4);
        s = fmaf(a.x, kr[i*4+0], s);
        s = fmaf(a.y, kr[i*4+1], s);
        s = fmaf(a.z, kr[i*4+2], s);
        s = fmaf(a.w, kr[i*4+3], s);
    }
    return s;
}
__device__ __forceinline__ int child32(int s, int c) {
    return (((s >> 4)*2 + (c >> 1)) << 5) + ((s & 15)*2 + (c & 1));
}
__device__ __forceinline__ int child64(int g, int c) {
    return (((g >> 5)*2 + (c >> 1)) << 6) + ((g & 31)*2 + (c & 1));
}
__device__ __forceinline__ int lanes_below(unsigned long long m, int lane) {
    return __builtin_amdgcn_mbcnt_hi((unsigned)(m >> 32),
             __builtin_amdgcn_mbcnt_lo((unsigned)m, 0));
}

// per-context arena layout (floats), 796 total:
//   [0..572)   scores (stage A pad, stage D at +288, stage F both)
//   OUTT = 0   output staging, written only after all score reads (stage F)
//   [556..572) W0V  (dead before stage-F scores overwrite)
//   [572..588) W0P
//   [588..604) MSG0
//   [604..668) MSG1
//   [668..700) W1V  \ aliased by GT2 = GT entries [64..128) in stage F
//   [700..732) W1P  /
//   [732..796) GT   = GT entries [0..64)
#define OUTT 0
#define W0V  556
#define W0P  572
#define MSG0 588
#define MSG1 604
#define W1V  668
#define W1P  700
#define GT2  668
#define GT   732
#define ARENA 796

// ---------------- Repack: head-major Q + KV-interleaved ----------------
__global__ __launch_bounds__(256) void k_repack(
    const float* __restrict__ q1, const float* __restrict__ k1, const float* __restrict__ v1,
    const float* __restrict__ q2, const float* __restrict__ k2, const float* __restrict__ v2,
    float* __restrict__ Q1h, float* __restrict__ KV1,
    float* __restrict__ Q2h, float* __restrict__ KV2)
{
    const int x = blockIdx.x, n = blockIdx.y, b = blockIdx.z;
    const int t = threadIdx.x;
    __shared__ float tA[16][129];
    __shared__ float tB[16][129];

    if (x < 20) {
        const float* src; float* dst; int S, ck;
        if (x < 4) { src = q1; dst = Q1h; S = 1024; ck = x; }
        else       { src = q2; dst = Q2h; S = 4096; ck = x - 4; }
        const int tok0 = ck * 256;
        const float* sp = src + ((size_t)(b*128 + n*16))*S + tok0;
        const int col = t & 127, half = t >> 7;
        #pragma unroll
        for (int j = 0; j < 8; ++j) {
            const int row = j*2 + half;
            tA[row][col] = sp[(size_t)row*S + col];
            tB[row][col] = sp[(size_t)row*S + col + 128];
        }
        __syncthreads();
        float* dp = dst + ((size_t)((b*8 + n)*S) + tok0 + t)*16;
        #pragma unroll
        for (int i = 0; i < 4; ++i) {
            float4 o;
            o.x = (half ? tB : tA)[i*4+0][col];
            o.y = (half ? tB : tA)[i*4+1][col];
            o.z = (half ? tB : tA)[i*4+2][col];
            o.w = (half ? tB : tA)[i*4+3][col];
            *(float4*)(dp + i*4) = o;
        }
    } else {
        const float* sK; const float* sV; float* dst; int S, ck;
        if (x < 28) { sK = k1; sV = v1; dst = KV1; S = 1024; ck = x - 20; }
        else        { sK = k2; sV = v2; dst = KV2; S = 4096; ck = x - 28; }
        const int tok0 = ck * 128;
        const int col = t & 127, rp = t >> 7;
        const float* kp = sK + ((size_t)(b*128 + n*16))*S + tok0;
        const float* vp = sV + ((size_t)(b*128 + n*16))*S + tok0;
        #pragma unroll
        for (int j = 0; j < 8; ++j) {
            const int row = j*2 + rp;
            tA[row][col] = kp[(size_t)row*S + col];
            tB[row][col] = vp[(size_t)row*S + col];
        }
        __syncthreads();
        const int tok = t >> 1, half = t & 1;
        float* dp = dst + (((size_t)((b*8 + n)*S) + tok0 + tok))*32 + half*16;
        #pragma unroll
        for (int i = 0; i < 4; ++i) {
            float4 o;
            o.x = (half ? tB : tA)[i*4+0][tok];
            o.y = (half ? tB : tA)[i*4+1][tok];
            o.z = (half ? tB : tA)[i*4+2][tok];
            o.w = (half ? tB : tA)[i*4+3][tok];
            *(float4*)(dp + i*4) = o;
        }
    }
}

// ---------------- Fused 3-level subtree kernel, 2 subtrees/wave ---------
// grid (1024,1,1) x 256. id = (lpair<<3) | (b<<1) | nh.
__global__ __launch_bounds__(256, 4) void k_fused(
    const float* __restrict__ q0, const float* __restrict__ k0, const float* __restrict__ v0,
    const float* __restrict__ Q1h, const float* __restrict__ KV1,
    const float* __restrict__ Q2h, const float* __restrict__ KV2,
    float* __restrict__ out)
{
    const int tid = threadIdx.x, lane = tid & 63, wid = tid >> 6;
    const int id    = blockIdx.x;
    const int nh    = id & 1;
    const int b     = (id >> 1) & 3;
    const int lpair = id >> 3;               // 0..127
    const int n     = nh*4 + wid;
    const int l0b   = lpair*2;               // even
    const int H0 = l0b >> 4, W0b = l0b & 15; // both contexts share H0; W0u=W0b+u

    __shared__ float arenaAll[4][2][ARENA];
    float* const A0 = arenaAll[wid][0];
    float* const A1 = arenaAll[wid][1];

    const float* Q1hh = Q1h + (size_t)((b*8 + n)*1024)*16;
    const float* KV1h = KV1 + (size_t)((b*8 + n)*1024)*32;
    const float* Q2hh = Q2h + (size_t)((b*8 + n)*4096)*16;
    const float* KV2h = KV2 + (size_t)((b*8 + n)*4096)*32;

    // ======== stage A: lvl0 scores, K shared, q as float2 ========
    const float* qb = q0 + ((size_t)(b*128 + n*16))*256 + l0b;
    const float* kb = k0 + ((size_t)(b*128 + n*16))*256 + lane*4;
    float2 q2r[16];
    #pragma unroll
    for (int dd = 0; dd < 16; ++dd) q2r[dd] = *(const float2*)(qb + (size_t)dd*256);
    float pA[4] = {0.f,0.f,0.f,0.f}, pB[4] = {0.f,0.f,0.f,0.f};
    #pragma unroll
    for (int dd = 0; dd < 16; ++dd) {
        float4 kv = *(const float4*)(kb + (size_t)dd*256);
        pA[0] = fmaf(q2r[dd].x, kv.x, pA[0]);
        pA[1] = fmaf(q2r[dd].x, kv.y, pA[1]);
        pA[2] = fmaf(q2r[dd].x, kv.z, pA[2]);
        pA[3] = fmaf(q2r[dd].x, kv.w, pA[3]);
        pB[0] = fmaf(q2r[dd].y, kv.x, pB[0]);
        pB[1] = fmaf(q2r[dd].y, kv.y, pB[1]);
        pB[2] = fmaf(q2r[dd].y, kv.z, pB[2]);
        pB[3] = fmaf(q2r[dd].y, kv.w, pB[3]);
    }
    #pragma unroll
    for (int j = 0; j < 4; ++j) { pA[j] *= 0.25f; pB[j] *= 0.25f; }
    float mA = fmaxf(fmaxf(pA[0], pA[1]), fmaxf(pA[2], pA[3]));
    float mB = fmaxf(fmaxf(pB[0], pB[1]), fmaxf(pB[2], pB[3]));
    mA = wavemax(mA); mB = wavemax(mB);
    float lsA = 0.f, lsB = 0.f;
    #pragma unroll
    for (int j = 0; j < 4; ++j) {
        pA[j] = expf(pA[j] - mA); lsA += pA[j];
        pB[j] = expf(pB[j] - mB); lsB += pB[j];
    }
    const float invA = 1.f / wavesum(lsA);
    const float invB = 1.f / wavesum(lsB);
    #pragma unroll
    for (int j = 0; j < 4; ++j) { pA[j] *= invA; pB[j] *= invB; }

    const int li = lane & 15;

    // ======== stage B: top-16 of 256 via bit-pattern bisection ========
    // Values are softmax probs in (0,1): float order == uint bit order.
    // Find t* with count(p > t*) == 16; count via v_cmp+ballot (VALU) and
    // SALU popcount. Early exit on exact count; <=30 iterations bounded
    // (initial span 2^30). If a 16/17 tie makes count==16 unreachable
    // (prob ~0), exits at lo+1==hi with count(>lo)>=16; rank cap keeps 16.
    unsigned tbA, tbB;
    {
        unsigned loA = 0u, hiA = 0x3F800000u;   // (0, 1.0f)
        unsigned loB = 0u, hiB = 0x3F800000u;
        bool dA = false, dB = false;
        #pragma unroll 1
        for (int it = 0; it < 34 && (!dA || !dB); ++it) {
            const unsigned mdA = (loA + hiA) >> 1;
            const unsigned mdB = (loB + hiB) >> 1;
            const float tA = __uint_as_float(mdA);
            const float tB = __uint_as_float(mdB);
            int cA = __popcll(__ballot(pA[0] > tA)) + __popcll(__ballot(pA[1] > tA))
                   + __popcll(__ballot(pA[2] > tA)) + __popcll(__ballot(pA[3] > tA));
            int cB = __popcll(__ballot(pB[0] > tB)) + __popcll(__ballot(pB[1] > tB))
                   + __popcll(__ballot(pB[2] > tB)) + __popcll(__ballot(pB[3] > tB));
            if (!dA) {
                if (cA == 16)     { loA = mdA; dA = true; }
                else if (cA > 16) { loA = mdA; }
                else              { hiA = mdA; }
                if (loA + 1 >= hiA) dA = true;
            }
            if (!dB) {
                if (cB == 16)     { loB = mdB; dB = true; }
                else if (cB > 16) { loB = mdB; }
                else              { hiB = mdB; }
                if (loB + 1 >= hiB) dB = true;
            }
        }
        tbA = loA; tbB = loB;
    }
    // winners -> W0V/W0P (unsorted; downstream uses value-pos pairs only)
    // via ballot+mbcnt prefix compaction; mask applied directly to p.
    {
        const float thA = __uint_as_float(tbA);
        const float thB = __uint_as_float(tbB);
        int baseA = 0, baseB = 0;
        #pragma unroll
        for (int j = 0; j < 4; ++j) {
            const bool wA = (pA[j] > thA);
            const bool wB = (pB[j] > thB);
            const unsigned long long mAj = __ballot(wA);
            const unsigned long long mBj = __ballot(wB);
            if (wA) {
                const int rank = baseA + lanes_below(mAj, lane);
                if (rank < 16) {
                    A0[W0V + rank] = pA[j];
                    A0[W0P + rank] = __int_as_float(lane*4 + j);
                }
                pA[j] = 0.f;
            }
            if (wB) {
                const int rank = baseB + lanes_below(mBj, lane);
                if (rank < 16) {
                    A1[W0V + rank] = pB[j];
                    A1[W0P + rank] = __int_as_float(lane*4 + j);
                }
                pB[j] = 0.f;
            }
            baseA += __popcll(mAj);
            baseB += __popcll(mBj);
        }
        // padded store of masked probs for stage C
        const int pad = lane*4 + 4*(lane>>4);
        *(float4*)&A0[pad] = make_float4(pA[0], pA[1], pA[2], pA[3]);
        *(float4*)&A1[pad] = make_float4(pB[0], pB[1], pB[2], pB[3]);
    }

    // ======== early lvl1 child table + K prefetch (both contexts) ========
    float kr1[2][16];
    float psD[2];
    {
        const int kp = lane >> 2, ci = lane & 3;
        #pragma unroll
        for (int u = 0; u < 2; ++u) {
            float* A = u ? A1 : A0;
            psD[u] = A[W0V + kp];
            const int spos = __float_as_int(A[W0P + kp]);
            const int g1 = child32(spos, ci);
            A[GT + lane] = __int_as_float(g1);
            const float* kv = KV1h + (size_t)g1*32;
            #pragma unroll
            for (int i = 0; i < 4; ++i) *(float4*)&kr1[u][i*4] = *(const float4*)(kv + i*4);
        }
    }

    // ======== stage C: msg0, V loads shared across contexts ========
    {
        const int dd = lane & 15, chunk = lane >> 4;
        const float* vb = v0 + ((size_t)(b*128 + n*16 + dd))*256 + chunk*64;
        float a0 = 0.f, a1 = 0.f;
        #pragma unroll
        for (int jj = 0; jj < 16; ++jj) {
            float4 vv = *(const float4*)(vb + jj*4);
            float4 p0 = *(const float4*)&A0[chunk*68 + jj*4];
            float4 p1 = *(const float4*)&A1[chunk*68 + jj*4];
            a0 = fmaf(p0.x, vv.x, a0); a0 = fmaf(p0.y, vv.y, a0);
            a0 = fmaf(p0.z, vv.z, a0); a0 = fmaf(p0.w, vv.w, a0);
            a1 = fmaf(p1.x, vv.x, a1); a1 = fmaf(p1.y, vv.y, a1);
            a1 = fmaf(p1.z, vv.z, a1); a1 = fmaf(p1.w, vv.w, a1);
        }
        a0 += __shfl_xor(a0, 16); a0 += __shfl_xor(a0, 32);
        a1 += __shfl_xor(a1, 16); a1 += __shfl_xor(a1, 32);
        if (lane < 16) { A0[MSG0 + dd] = a0; A1[MSG0 + dd] = a1; }
    }

    // ======== stage D: lvl1 scoring (kr1 preloaded) + top-8 ========
    #pragma unroll
    for (int u = 0; u < 2; ++u) {
        float* A = u ? A1 : A0;
        const int W0u = W0b + u;
        #pragma unroll
        for (int t = 0; t < 4; ++t) {
            const int qtok = ((2*H0 + (t>>1)) << 5) + 2*W0u + (t&1);
            float sc = dot16(Q1hh + qtok*16, kr1[u]) * 0.25f;
            const float mm = quadmax4(sc);
            const float e  = expf(sc - mm);
            const float su = quadsum4(e);
            A[288 + t*68 + lane] = (e / su) * psD[u];
        }
    }
    {
        const int tg = lane >> 4;
        float r[2][4];
        {
            float4 t0 = *(const float4*)&A0[288 + tg*68 + li*4];
            float4 t1 = *(const float4*)&A1[288 + tg*68 + li*4];
            r[0][0] = t0.x; r[0][1] = t0.y; r[0][2] = t0.z; r[0][3] = t0.w;
            r[1][0] = t1.x; r[1][1] = t1.y; r[1][2] = t1.z; r[1][3] = t1.w;
        }
        float cv1[2] = {0.f, 0.f}; int cs1[2] = {0, 0};
        #pragma unroll 1
        for (int it = 0; it < 8; ++it) {
            #pragma unroll
            for (int u = 0; u < 2; ++u) {
                float bv = fmaxf(fmaxf(r[u][0], r[u][1]), fmaxf(r[u][2], r[u][3]));
                bv = rowmax16(bv);
                int cs = 0x7FFFFFFF;
                cs = (r[u][3] == bv) ? (li*4 + 3) : cs;
                cs = (r[u][2] == bv) ? (li*4 + 2) : cs;
                cs = (r[u][1] == bv) ? (li*4 + 1) : cs;
                cs = (r[u][0] == bv) ? (li*4 + 0) : cs;
                cs = rowmin16i(cs);
                r[u][0] = (cs == li*4 + 0) ? 0.f : r[u][0];
                r[u][1] = (cs == li*4 + 1) ? 0.f : r[u][1];
                r[u][2] = (cs == li*4 + 2) ? 0.f : r[u][2];
                r[u][3] = (cs == li*4 + 3) ? 0.f : r[u][3];
                if (li == it) { cv1[u] = bv; cs1[u] = cs; }
            }
        }
        #pragma unroll
        for (int u = 0; u < 2; ++u) {
            float* A = u ? A1 : A0;
            *(float4*)&A[288 + tg*68 + li*4] =
                make_float4(r[u][0], r[u][1], r[u][2], r[u][3]);
            if (li < 8) {
                A[W1V + tg*8 + li] = cv1[u];
                A[W1P + tg*8 + li] = A[GT + cs1[u]];
            }
        }
    }

    // ======== stage E: msg1 per context ========
    {
        const int ks = lane >> 4, t2 = (lane >> 2) & 3, dq = lane & 3;
        #pragma unroll
        for (int u = 0; u < 2; ++u) {
            float* A = u ? A1 : A0;
            float4 acc = make_float4(0.f, 0.f, 0.f, 0.f);
            #pragma unroll
            for (int jj = 0; jj < 4; ++jj) {
                float4 pv = *(const float4*)&A[288 + t2*68 + ks*16 + jj*4];
                const float pa[4] = {pv.x, pv.y, pv.z, pv.w};
                #pragma unroll
                for (int c = 0; c < 4; ++c) {
                    const int g = __float_as_int(A[GT + ks*16 + jj*4 + c]);
                    float4 vv = *(const float4*)(KV1h + (size_t)g*32 + 16 + dq*4);
                    acc.x = fmaf(pa[c], vv.x, acc.x);
                    acc.y = fmaf(pa[c], vv.y, acc.y);
                    acc.z = fmaf(pa[c], vv.z, acc.z);
                    acc.w = fmaf(pa[c], vv.w, acc.w);
                }
            }
            acc.x += __shfl_xor(acc.x, 16); acc.y += __shfl_xor(acc.y, 16);
            acc.z += __shfl_xor(acc.z, 16); acc.w += __shfl_xor(acc.w, 16);
            acc.x += __shfl_xor(acc.x, 32); acc.y += __shfl_xor(acc.y, 32);
            acc.z += __shfl_xor(acc.z, 32); acc.w += __shfl_xor(acc.w, 32);
            if (lane < 16)
                *(float4*)&A[MSG1 + t2*16 + dq*4] = acc;
        }
    }

    // ======== stage F: lvl2 ========
    {
        const int t1h = lane >> 5, kk = lane & 31;
        const int kp2 = kk >> 2, ci2 = kk & 3;
        float krA[2][16], krB[2][16];
        float psA[2], psB[2];
        // GT fill + all K loads up front (one wall).
        // NOTE: GT2 aliases W1V/W1P — all W1V/W1P reads MUST precede the
        // GT writes (per-wave LDS ops execute in program order).
        #pragma unroll
        for (int u = 0; u < 2; ++u) {
            float* A = u ? A1 : A0;
            const int wpA = __float_as_int(A[W1P + t1h*8 + kp2]);
            const int wpB = __float_as_int(A[W1P + (2+t1h)*8 + kp2]);
            psA[u] = A[W1V + t1h*8 + kp2];
            psB[u] = A[W1V + (2+t1h)*8 + kp2];
            const int gA = child64(wpA, ci2);
            const int gB = child64(wpB, ci2);
            A[GT  + t1h*32 + kk] = __int_as_float(gA);   // GT idx [0..64)
            A[GT2 + t1h*32 + kk] = __int_as_float(gB);   // GT idx [64..128)
            const float* kva = KV2h + (size_t)gA*32;
            const float* kvb = KV2h + (size_t)gB*32;
            #pragma unroll
            for (int i = 0; i < 4; ++i) {
                *(float4*)&krA[u][i*4] = *(const float4*)(kva + i*4);
                *(float4*)&krB[u][i*4] = *(const float4*)(kvb + i*4);
            }
        }
        // score pass 0 (t1 = t1h) and pass 1 (t1 = 2+t1h) per context
        #pragma unroll
        for (int u = 0; u < 2; ++u) {
            float* A = u ? A1 : A0;
            const int W0u = W0b + u;
            {
                const int t1 = t1h;
                const int y1 = 2*H0 + (t1 >> 1), x1 = 2*W0u + (t1 & 1);
                #pragma unroll
                for (int t2 = 0; t2 < 4; ++t2) {
                    const int qtok2 = ((2*y1 + (t2>>1)) << 6) + 2*x1 + (t2&1);
                    float sc = dot16(Q2hh + qtok2*16, krA[u]) * 0.25f;
                    const float mm = quadmax4(sc);
                    const float e  = expf(sc - mm);
                    const float su = quadsum4(e);
                    A[t1h*144 + t2*36 + kk] = (e / su) * psA[u];
                }
            }
            {
                const int t1 = 2 + t1h;
                const int y1 = 2*H0 + (t1 >> 1), x1 = 2*W0u + (t1 & 1);
                #pragma unroll
                for (int t2 = 0; t2 < 4; ++t2) {
                    const int qtok2 = ((2*y1 + (t2>>1)) << 6) + 2*x1 + (t2&1);
                    float sc = dot16(Q2hh + qtok2*16, krB[u]) * 0.25f;
                    const float mm = quadmax4(sc);
                    const float e  = expf(sc - mm);
                    const float su = quadsum4(e);
                    A[288 + t1h*144 + t2*36 + kk] = (e / su) * psB[u];
                }
            }
        }
    }
    // msg halves per context. OUTT overlaps the score region, so both
    // h-accumulators are finished in registers before any OUTT store.
    {
        const int ks2 = lane >> 5, qq = (lane >> 2) & 7, dq = lane & 3;
        const int t1l = qq >> 2, t2 = qq & 3;
        #pragma unroll
        for (int u = 0; u < 2; ++u) {
            float* A = u ? A1 : A0;
            float4 accs[2];
            #pragma unroll
            for (int h = 0; h < 2; ++h) {
                const int t1 = h*2 + t1l;
                const int sb = (t1 >> 1)*288 + (t1 & 1)*144 + t2*36;
                const int gtb = (h == 0) ? GT : GT2;   // GT idx [0..64) / [64..128)
                float4 acc = make_float4(0.f, 0.f, 0.f, 0.f);
                #pragma unroll
                for (int j4 = 0; j4 < 4; ++j4) {
                    float4 pv = *(const float4*)&A[sb + ks2*16 + j4*4];
                    const float pa[4] = {pv.x, pv.y, pv.z, pv.w};
                    #pragma unroll
                    for (int c = 0; c < 4; ++c) {
                        const int g2 = __float_as_int(A[gtb + t1l*32 + ks2*16 + j4*4 + c]);
                        float4 vv = *(const float4*)(KV2h + (size_t)g2*32 + 16 + dq*4);
                        acc.x = fmaf(pa[c], vv.x, acc.x);
                        acc.y = fmaf(pa[c], vv.y, acc.y);
                        acc.z = fmaf(pa[c], vv.z, acc.z);
                        acc.w = fmaf(pa[c], vv.w, acc.w);
                    }
                }
                acc.x += __shfl_xor(acc.x, 32); acc.y += __shfl_xor(acc.y, 32);
                acc.z += __shfl_xor(acc.z, 32); acc.w += __shfl_xor(acc.w, 32);
                float4 m1 = *(const float4*)&A[MSG1 + t1*16 + dq*4];
                float4 m0 = *(const float4*)&A[MSG0 + dq*4];
                acc.x += m1.x + m0.x;
                acc.y += m1.y + m0.y;
                acc.z += m1.z + m0.z;
                acc.w += m1.w + m0.w;
                accs[h] = acc;
            }
            if (lane < 32) {
                *(float4*)&A[OUTT + ((t1l    )*4 + t2)*16 + dq*4] = accs[0];
                *(float4*)&A[OUTT + ((2 + t1l)*4 + t2)*16 + dq*4] = accs[1];
            }
        }
    }

    // ======== output: two adjacent 4x4 patches (same rows) ========
    {
        const int y = lane & 3, dd = lane >> 2;
        #pragma unroll
        for (int u = 0; u < 2; ++u) {
            float* A = u ? A1 : A0;
            const int W0u = W0b + u;
            float vr[4];
            #pragma unroll
            for (int x = 0; x < 4; ++x) {
                const int t1 = (((y>>1) << 1) | (x>>1));
                const int t2 = (((y&1)  << 1) | (x&1));
                vr[x] = A[OUTT + (t1*4 + t2)*16 + dd];
            }
            float* op = out + (((size_t)(b*128 + n*16 + dd)*64 + 4*H0 + y))*64 + 4*W0u;
            *(float4*)op = make_float4(vr[0], vr[1], vr[2], vr[3]);
        }
    }
}

extern "C" void kernel_launch(void* const* d_in, const int* in_sizes, int n_in,
                              void* d_out, int out_size, void* d_ws, size_t ws_size,
                              hipStream_t stream)
{
    const float* q0 = (const float*)d_in[0];
    const float* k0 = (const float*)d_in[1];
    const float* v0 = (const float*)d_in[2];
    const float* q1 = (const float*)d_in[3];
    const float* k1 = (const float*)d_in[4];
    const float* v1 = (const float*)d_in[5];
    const float* q2 = (const float*)d_in[6];
    const float* k2 = (const float*)d_in[7];
    const float* v2 = (const float*)d_in[8];

    float* ws  = (float*)d_ws;
    float* Q1h = ws;                 // 4*8*1024*16 = 524288
    float* KV1 = ws + 524288;        // 4*8*1024*32 = 1048576
    float* Q2h = ws + 1572864;       // 4*8*4096*16 = 2097152
    float* KV2 = ws + 3670016;       // 4*8*4096*32 = 4194304

    k_repack<<<dim3(60, 8, 4), 256, 0, stream>>>(q1, k1, v1, q2, k2, v2,
                                                 Q1h, KV1, Q2h, KV2);
    k_fused<<<dim3(1024, 1, 1), 256, 0, stream>>>(q0, k0, v0,
                                                  Q1h, KV1, Q2h, KV2,
                                                  (float*)d_out);
}

// Round 5
// 147.694 us; speedup vs baseline: 1.1584x; 1.0352x over previous
//
#include <hip/hip_runtime.h>
#include <cstddef>

// QuadTree attention, 3 levels. B=4, C=128, NHEAD=8, d=16.
// Grids: 16x16 (S=256), 32x32 (S=1024), 64x64 (S=4096). TOPKS=(16,8,8).
//
// R14: R13 + two stall-removal changes:
//  1) Q-hoist: stage D/F read Q1h/Q2h via per-lane global loads inside the
//     scoring loops (80 float4/lane, address = f(H0,W0) only, ~200cy L2
//     latency each, serialized by the 64-VGPR budget). Now staged once
//     cooperatively into LDS (Q1T/Q2T) right after stage A's FMA loop,
//     overlapped with the pure-VALU stage B; dot16 reads LDS broadcast.
//     LDS arena 796 -> 1120 floats (35840B/block) is free: occupancy is
//     grid-capped at 4 blocks/CU (1024 blocks/256 CU), not LDS-capped.
//  2) Stage-D top-8 of 64 via bit-pattern bisection (R13 stage-B method,
//     per-16-lane-group): ballot slices + popcount replace the 8-iteration
//     rowmax16/rowmin16i DPP extraction chain. Winners compacted to
//     W1V/W1P by intra-group prefix ranks (unsorted; downstream uses
//     value-pos pairs only). Tie semantics as R13 (prob ~0).
// XCD swizzle id&7=(b<<1)|nh keeps per-XCD KV working set in XCD L2.

#define DPP_QUAD_X1 0xB1
#define DPP_QUAD_X2 0x4E
#define DPP_ROR_1   0x121
#define DPP_ROR_2   0x122
#define DPP_ROR_4   0x124
#define DPP_ROR_8   0x128

template<int C>
__device__ __forceinline__ int dpp_i(int x) {
    return __builtin_amdgcn_mov_dpp(x, C, 0xF, 0xF, true);
}
template<int C>
__device__ __forceinline__ float dpp_f(float x) {
    return __int_as_float(__builtin_amdgcn_mov_dpp(__float_as_int(x), C, 0xF, 0xF, true));
}
__device__ __forceinline__ float rowmax16(float x) {
    x = fmaxf(x, dpp_f<DPP_ROR_1>(x));
    x = fmaxf(x, dpp_f<DPP_ROR_2>(x));
    x = fmaxf(x, dpp_f<DPP_ROR_4>(x));
    x = fmaxf(x, dpp_f<DPP_ROR_8>(x));
    return x;
}
__device__ __forceinline__ float quadmax4(float x) {
    x = fmaxf(x, dpp_f<DPP_QUAD_X1>(x));
    x = fmaxf(x, dpp_f<DPP_QUAD_X2>(x));
    return x;
}
__device__ __forceinline__ float quadsum4(float x) {
    x += dpp_f<DPP_QUAD_X1>(x);
    x += dpp_f<DPP_QUAD_X2>(x);
    return x;
}
__device__ __forceinline__ float wavemax(float x) {
    x = rowmax16(x);
    x = fmaxf(x, __shfl_xor(x, 16));
    x = fmaxf(x, __shfl_xor(x, 32));
    return x;
}
__device__ __forceinline__ float wavesum(float x) {
    x += dpp_f<DPP_ROR_1>(x); x += dpp_f<DPP_ROR_2>(x);
    x += dpp_f<DPP_ROR_4>(x); x += dpp_f<DPP_ROR_8>(x);
    x += __shfl_xor(x, 16);   x += __shfl_xor(x, 32);
    return x;
}
__device__ __forceinline__ float dot16(const float* qp, const float* kr) {
    float s = 0.f;
    #pragma unroll
    for (int i = 0; i < 4; ++i) {
        float4 a = *(const float4*)(qp + i*4);
        s = fmaf(a.x, kr[i*4+0], s);
        s = fmaf(a.y, kr[i*4+1], s);
        s = fmaf(a.z, kr[i*4+2], s);
        s = fmaf(a.w, kr[i*4+3], s);
    }
    return s;
}
__device__ __forceinline__ int child32(int s, int c) {
    return (((s >> 4)*2 + (c >> 1)) << 5) + ((s & 15)*2 + (c & 1));
}
__device__ __forceinline__ int child64(int g, int c) {
    return (((g >> 5)*2 + (c >> 1)) << 6) + ((g & 31)*2 + (c & 1));
}
__device__ __forceinline__ int lanes_below(unsigned long long m, int lane) {
    return __builtin_amdgcn_mbcnt_hi((unsigned)(m >> 32),
             __builtin_amdgcn_mbcnt_lo((unsigned)m, 0));
}

// per-context arena layout (floats), 1120 total:
//   [0..572)    scores (stage A pad, stage D at +288, stage F both)
//   OUTT = 0    output staging, written only after all score reads (stage F)
//   [556..572)  W0V  (dead before stage-F scores overwrite)
//   [572..588)  W0P
//   [588..604)  MSG0
//   [604..668)  MSG1
//   [668..700)  W1V  \ aliased by GT2 = GT entries [64..128) in stage F
//   [700..732)  W1P  /
//   [732..796)  GT   = GT entries [0..64)
//   [800..864)  Q1T  staged lvl1 Q tokens (4 x 16 floats)
//   [864..1120) Q2T  staged lvl2 Q tokens (16 x 16 floats)
#define OUTT 0
#define W0V  556
#define W0P  572
#define MSG0 588
#define MSG1 604
#define W1V  668
#define W1P  700
#define GT2  668
#define GT   732
#define Q1T  800
#define Q2T  864
#define ARENA 1120

// ---------------- Repack: head-major Q + KV-interleaved ----------------
__global__ __launch_bounds__(256) void k_repack(
    const float* __restrict__ q1, const float* __restrict__ k1, const float* __restrict__ v1,
    const float* __restrict__ q2, const float* __restrict__ k2, const float* __restrict__ v2,
    float* __restrict__ Q1h, float* __restrict__ KV1,
    float* __restrict__ Q2h, float* __restrict__ KV2)
{
    const int x = blockIdx.x, n = blockIdx.y, b = blockIdx.z;
    const int t = threadIdx.x;
    __shared__ float tA[16][129];
    __shared__ float tB[16][129];

    if (x < 20) {
        const float* src; float* dst; int S, ck;
        if (x < 4) { src = q1; dst = Q1h; S = 1024; ck = x; }
        else       { src = q2; dst = Q2h; S = 4096; ck = x - 4; }
        const int tok0 = ck * 256;
        const float* sp = src + ((size_t)(b*128 + n*16))*S + tok0;
        const int col = t & 127, half = t >> 7;
        #pragma unroll
        for (int j = 0; j < 8; ++j) {
            const int row = j*2 + half;
            tA[row][col] = sp[(size_t)row*S + col];
            tB[row][col] = sp[(size_t)row*S + col + 128];
        }
        __syncthreads();
        float* dp = dst + ((size_t)((b*8 + n)*S) + tok0 + t)*16;
        #pragma unroll
        for (int i = 0; i < 4; ++i) {
            float4 o;
            o.x = (half ? tB : tA)[i*4+0][col];
            o.y = (half ? tB : tA)[i*4+1][col];
            o.z = (half ? tB : tA)[i*4+2][col];
            o.w = (half ? tB : tA)[i*4+3][col];
            *(float4*)(dp + i*4) = o;
        }
    } else {
        const float* sK; const float* sV; float* dst; int S, ck;
        if (x < 28) { sK = k1; sV = v1; dst = KV1; S = 1024; ck = x - 20; }
        else        { sK = k2; sV = v2; dst = KV2; S = 4096; ck = x - 28; }
        const int tok0 = ck * 128;
        const int col = t & 127, rp = t >> 7;
        const float* kp = sK + ((size_t)(b*128 + n*16))*S + tok0;
        const float* vp = sV + ((size_t)(b*128 + n*16))*S + tok0;
        #pragma unroll
        for (int j = 0; j < 8; ++j) {
            const int row = j*2 + rp;
            tA[row][col] = kp[(size_t)row*S + col];
            tB[row][col] = vp[(size_t)row*S + col];
        }
        __syncthreads();
        const int tok = t >> 1, half = t & 1;
        float* dp = dst + (((size_t)((b*8 + n)*S) + tok0 + tok))*32 + half*16;
        #pragma unroll
        for (int i = 0; i < 4; ++i) {
            float4 o;
            o.x = (half ? tB : tA)[i*4+0][tok];
            o.y = (half ? tB : tA)[i*4+1][tok];
            o.z = (half ? tB : tA)[i*4+2][tok];
            o.w = (half ? tB : tA)[i*4+3][tok];
            *(float4*)(dp + i*4) = o;
        }
    }
}

// ---------------- Fused 3-level subtree kernel, 2 subtrees/wave ---------
// grid (1024,1,1) x 256. id = (lpair<<3) | (b<<1) | nh.
__global__ __launch_bounds__(256, 4) void k_fused(
    const float* __restrict__ q0, const float* __restrict__ k0, const float* __restrict__ v0,
    const float* __restrict__ Q1h, const float* __restrict__ KV1,
    const float* __restrict__ Q2h, const float* __restrict__ KV2,
    float* __restrict__ out)
{
    const int tid = threadIdx.x, lane = tid & 63, wid = tid >> 6;
    const int id    = blockIdx.x;
    const int nh    = id & 1;
    const int b     = (id >> 1) & 3;
    const int lpair = id >> 3;               // 0..127
    const int n     = nh*4 + wid;
    const int l0b   = lpair*2;               // even
    const int H0 = l0b >> 4, W0b = l0b & 15; // both contexts share H0; W0u=W0b+u

    __shared__ float arenaAll[4][2][ARENA];
    float* const A0 = arenaAll[wid][0];
    float* const A1 = arenaAll[wid][1];

    const float* Q1hh = Q1h + (size_t)((b*8 + n)*1024)*16;
    const float* KV1h = KV1 + (size_t)((b*8 + n)*1024)*32;
    const float* Q2hh = Q2h + (size_t)((b*8 + n)*4096)*16;
    const float* KV2h = KV2 + (size_t)((b*8 + n)*4096)*32;

    // ======== stage A: lvl0 scores, K shared, q as float2 ========
    const float* qb = q0 + ((size_t)(b*128 + n*16))*256 + l0b;
    const float* kb = k0 + ((size_t)(b*128 + n*16))*256 + lane*4;
    float2 q2r[16];
    #pragma unroll
    for (int dd = 0; dd < 16; ++dd) q2r[dd] = *(const float2*)(qb + (size_t)dd*256);
    float pA[4] = {0.f,0.f,0.f,0.f}, pB[4] = {0.f,0.f,0.f,0.f};
    #pragma unroll
    for (int dd = 0; dd < 16; ++dd) {
        float4 kv = *(const float4*)(kb + (size_t)dd*256);
        pA[0] = fmaf(q2r[dd].x, kv.x, pA[0]);
        pA[1] = fmaf(q2r[dd].x, kv.y, pA[1]);
        pA[2] = fmaf(q2r[dd].x, kv.z, pA[2]);
        pA[3] = fmaf(q2r[dd].x, kv.w, pA[3]);
        pB[0] = fmaf(q2r[dd].y, kv.x, pB[0]);
        pB[1] = fmaf(q2r[dd].y, kv.y, pB[1]);
        pB[2] = fmaf(q2r[dd].y, kv.z, pB[2]);
        pB[3] = fmaf(q2r[dd].y, kv.w, pB[3]);
    }

    // ======== Q-hoist: stage lvl1+lvl2 query tokens into LDS ========
    // Addresses depend only on (H0, W0b+u); issued here so the loads
    // overlap stage A softmax + stage B bisection (pure VALU). Same-wave
    // ds ordering makes them visible to stage D/F without barriers.
    {
        const int tt = lane >> 2, c4 = lane & 3;
        #pragma unroll
        for (int u = 0; u < 2; ++u) {
            float* A = u ? A1 : A0;
            if (lane < 16) {
                const int t = tt;  // 0..3
                const int qtok = ((2*H0 + (t>>1)) << 5) + 2*(W0b+u) + (t&1);
                *(float4*)&A[Q1T + t*16 + c4*4] =
                    *(const float4*)(Q1hh + (size_t)qtok*16 + c4*4);
            }
            const int t1 = tt >> 2, t2 = tt & 3;
            const int y1 = 2*H0 + (t1 >> 1), x1 = 2*(W0b+u) + (t1 & 1);
            const int qtok2 = ((2*y1 + (t2>>1)) << 6) + 2*x1 + (t2&1);
            *(float4*)&A[Q2T + tt*16 + c4*4] =
                *(const float4*)(Q2hh + (size_t)qtok2*16 + c4*4);
        }
    }

    #pragma unroll
    for (int j = 0; j < 4; ++j) { pA[j] *= 0.25f; pB[j] *= 0.25f; }
    float mA = fmaxf(fmaxf(pA[0], pA[1]), fmaxf(pA[2], pA[3]));
    float mB = fmaxf(fmaxf(pB[0], pB[1]), fmaxf(pB[2], pB[3]));
    mA = wavemax(mA); mB = wavemax(mB);
    float lsA = 0.f, lsB = 0.f;
    #pragma unroll
    for (int j = 0; j < 4; ++j) {
        pA[j] = expf(pA[j] - mA); lsA += pA[j];
        pB[j] = expf(pB[j] - mB); lsB += pB[j];
    }
    const float invA = 1.f / wavesum(lsA);
    const float invB = 1.f / wavesum(lsB);
    #pragma unroll
    for (int j = 0; j < 4; ++j) { pA[j] *= invA; pB[j] *= invB; }

    const int li = lane & 15;

    // ======== stage B: top-16 of 256 via bit-pattern bisection ========
    unsigned tbA, tbB;
    {
        unsigned loA = 0u, hiA = 0x3F800000u;   // (0, 1.0f)
        unsigned loB = 0u, hiB = 0x3F800000u;
        bool dA = false, dB = false;
        #pragma unroll 1
        for (int it = 0; it < 34 && (!dA || !dB); ++it) {
            const unsigned mdA = (loA + hiA) >> 1;
            const unsigned mdB = (loB + hiB) >> 1;
            const float tA = __uint_as_float(mdA);
            const float tB = __uint_as_float(mdB);
            int cA = __popcll(__ballot(pA[0] > tA)) + __popcll(__ballot(pA[1] > tA))
                   + __popcll(__ballot(pA[2] > tA)) + __popcll(__ballot(pA[3] > tA));
            int cB = __popcll(__ballot(pB[0] > tB)) + __popcll(__ballot(pB[1] > tB))
                   + __popcll(__ballot(pB[2] > tB)) + __popcll(__ballot(pB[3] > tB));
            if (!dA) {
                if (cA == 16)     { loA = mdA; dA = true; }
                else if (cA > 16) { loA = mdA; }
                else              { hiA = mdA; }
                if (loA + 1 >= hiA) dA = true;
            }
            if (!dB) {
                if (cB == 16)     { loB = mdB; dB = true; }
                else if (cB > 16) { loB = mdB; }
                else              { hiB = mdB; }
                if (loB + 1 >= hiB) dB = true;
            }
        }
        tbA = loA; tbB = loB;
    }
    {
        const float thA = __uint_as_float(tbA);
        const float thB = __uint_as_float(tbB);
        int baseA = 0, baseB = 0;
        #pragma unroll
        for (int j = 0; j < 4; ++j) {
            const bool wA = (pA[j] > thA);
            const bool wB = (pB[j] > thB);
            const unsigned long long mAj = __ballot(wA);
            const unsigned long long mBj = __ballot(wB);
            if (wA) {
                const int rank = baseA + lanes_below(mAj, lane);
                if (rank < 16) {
                    A0[W0V + rank] = pA[j];
                    A0[W0P + rank] = __int_as_float(lane*4 + j);
                }
                pA[j] = 0.f;
            }
            if (wB) {
                const int rank = baseB + lanes_below(mBj, lane);
                if (rank < 16) {
                    A1[W0V + rank] = pB[j];
                    A1[W0P + rank] = __int_as_float(lane*4 + j);
                }
                pB[j] = 0.f;
            }
            baseA += __popcll(mAj);
            baseB += __popcll(mBj);
        }
        // padded store of masked probs for stage C
        const int pad = lane*4 + 4*(lane>>4);
        *(float4*)&A0[pad] = make_float4(pA[0], pA[1], pA[2], pA[3]);
        *(float4*)&A1[pad] = make_float4(pB[0], pB[1], pB[2], pB[3]);
    }

    // ======== early lvl1 child table + K prefetch (both contexts) ========
    float kr1[2][16];
    float psD[2];
    {
        const int kp = lane >> 2, ci = lane & 3;
        #pragma unroll
        for (int u = 0; u < 2; ++u) {
            float* A = u ? A1 : A0;
            psD[u] = A[W0V + kp];
            const int spos = __float_as_int(A[W0P + kp]);
            const int g1 = child32(spos, ci);
            A[GT + lane] = __int_as_float(g1);
            const float* kv = KV1h + (size_t)g1*32;
            #pragma unroll
            for (int i = 0; i < 4; ++i) *(float4*)&kr1[u][i*4] = *(const float4*)(kv + i*4);
        }
    }

    // ======== stage C: msg0, V loads shared across contexts ========
    {
        const int dd = lane & 15, chunk = lane >> 4;
        const float* vb = v0 + ((size_t)(b*128 + n*16 + dd))*256 + chunk*64;
        float a0 = 0.f, a1 = 0.f;
        #pragma unroll
        for (int jj = 0; jj < 16; ++jj) {
            float4 vv = *(const float4*)(vb + jj*4);
            float4 p0 = *(const float4*)&A0[chunk*68 + jj*4];
            float4 p1 = *(const float4*)&A1[chunk*68 + jj*4];
            a0 = fmaf(p0.x, vv.x, a0); a0 = fmaf(p0.y, vv.y, a0);
            a0 = fmaf(p0.z, vv.z, a0); a0 = fmaf(p0.w, vv.w, a0);
            a1 = fmaf(p1.x, vv.x, a1); a1 = fmaf(p1.y, vv.y, a1);
            a1 = fmaf(p1.z, vv.z, a1); a1 = fmaf(p1.w, vv.w, a1);
        }
        a0 += __shfl_xor(a0, 16); a0 += __shfl_xor(a0, 32);
        a1 += __shfl_xor(a1, 16); a1 += __shfl_xor(a1, 32);
        if (lane < 16) { A0[MSG0 + dd] = a0; A1[MSG0 + dd] = a1; }
    }

    // ======== stage D: lvl1 scoring (kr1 preloaded, Q from LDS) + top-8 ====
    #pragma unroll
    for (int u = 0; u < 2; ++u) {
        float* A = u ? A1 : A0;
        #pragma unroll
        for (int t = 0; t < 4; ++t) {
            float sc = dot16(&A[Q1T + t*16], kr1[u]) * 0.25f;
            const float mm = quadmax4(sc);
            const float e  = expf(sc - mm);
            const float su = quadsum4(e);
            A[288 + t*68 + lane] = (e / su) * psD[u];
        }
    }
    {
        const int tg = lane >> 4;
        float r[2][4];
        {
            float4 t0 = *(const float4*)&A0[288 + tg*68 + li*4];
            float4 t1 = *(const float4*)&A1[288 + tg*68 + li*4];
            r[0][0] = t0.x; r[0][1] = t0.y; r[0][2] = t0.z; r[0][3] = t0.w;
            r[1][0] = t1.x; r[1][1] = t1.y; r[1][2] = t1.z; r[1][3] = t1.w;
        }
        // top-8 of 64 per (context, group) via group-local bisection
        const int sh = tg * 16;
        unsigned lo0 = 0u, hi0 = 0x3F800000u; bool d0 = false;
        unsigned lo1 = 0u, hi1 = 0x3F800000u; bool d1 = false;
        #pragma unroll 1
        for (int it = 0; it < 34; ++it) {
            if (__all(d0 && d1)) break;
            const unsigned md0 = (lo0 + hi0) >> 1;
            const unsigned md1 = (lo1 + hi1) >> 1;
            const float th0 = __uint_as_float(md0);
            const float th1 = __uint_as_float(md1);
            int c0 = 0, c1 = 0;
            #pragma unroll
            for (int j = 0; j < 4; ++j) {
                c0 += __popc((unsigned)((__ballot(r[0][j] > th0) >> sh) & 0xFFFFull));
                c1 += __popc((unsigned)((__ballot(r[1][j] > th1) >> sh) & 0xFFFFull));
            }
            if (!d0) {
                if (c0 == 8)     { lo0 = md0; d0 = true; }
                else if (c0 > 8) { lo0 = md0; }
                else             { hi0 = md0; }
                if (lo0 + 1 >= hi0) d0 = true;
            }
            if (!d1) {
                if (c1 == 8)     { lo1 = md1; d1 = true; }
                else if (c1 > 8) { lo1 = md1; }
                else             { hi1 = md1; }
                if (lo1 + 1 >= hi1) d1 = true;
            }
        }
        const float th0 = __uint_as_float(lo0);
        const float th1 = __uint_as_float(lo1);
        int base0 = 0, base1 = 0;
        const unsigned below = (1u << li) - 1u;
        #pragma unroll
        for (int j = 0; j < 4; ++j) {
            const unsigned s0 = (unsigned)((__ballot(r[0][j] > th0) >> sh) & 0xFFFFull);
            const unsigned s1 = (unsigned)((__ballot(r[1][j] > th1) >> sh) & 0xFFFFull);
            if (r[0][j] > th0) {
                const int rank = base0 + __popc(s0 & below);
                if (rank < 8) {
                    A0[W1V + tg*8 + rank] = r[0][j];
                    A0[W1P + tg*8 + rank] = A0[GT + li*4 + j];
                }
                r[0][j] = 0.f;
            }
            if (r[1][j] > th1) {
                const int rank = base1 + __popc(s1 & below);
                if (rank < 8) {
                    A1[W1V + tg*8 + rank] = r[1][j];
                    A1[W1P + tg*8 + rank] = A1[GT + li*4 + j];
                }
                r[1][j] = 0.f;
            }
            base0 += __popc(s0);
            base1 += __popc(s1);
        }
        *(float4*)&A0[288 + tg*68 + li*4] = make_float4(r[0][0], r[0][1], r[0][2], r[0][3]);
        *(float4*)&A1[288 + tg*68 + li*4] = make_float4(r[1][0], r[1][1], r[1][2], r[1][3]);
    }

    // ======== stage E: msg1 per context ========
    {
        const int ks = lane >> 4, t2 = (lane >> 2) & 3, dq = lane & 3;
        #pragma unroll
        for (int u = 0; u < 2; ++u) {
            float* A = u ? A1 : A0;
            float4 acc = make_float4(0.f, 0.f, 0.f, 0.f);
            #pragma unroll
            for (int jj = 0; jj < 4; ++jj) {
                float4 pv = *(const float4*)&A[288 + t2*68 + ks*16 + jj*4];
                const float pa[4] = {pv.x, pv.y, pv.z, pv.w};
                #pragma unroll
                for (int c = 0; c < 4; ++c) {
                    const int g = __float_as_int(A[GT + ks*16 + jj*4 + c]);
                    float4 vv = *(const float4*)(KV1h + (size_t)g*32 + 16 + dq*4);
                    acc.x = fmaf(pa[c], vv.x, acc.x);
                    acc.y = fmaf(pa[c], vv.y, acc.y);
                    acc.z = fmaf(pa[c], vv.z, acc.z);
                    acc.w = fmaf(pa[c], vv.w, acc.w);
                }
            }
            acc.x += __shfl_xor(acc.x, 16); acc.y += __shfl_xor(acc.y, 16);
            acc.z += __shfl_xor(acc.z, 16); acc.w += __shfl_xor(acc.w, 16);
            acc.x += __shfl_xor(acc.x, 32); acc.y += __shfl_xor(acc.y, 32);
            acc.z += __shfl_xor(acc.z, 32); acc.w += __shfl_xor(acc.w, 32);
            if (lane < 16)
                *(float4*)&A[MSG1 + t2*16 + dq*4] = acc;
        }
    }

    // ======== stage F: lvl2 ========
    {
        const int t1h = lane >> 5, kk = lane & 31;
        const int kp2 = kk >> 2, ci2 = kk & 3;
        float krA[2][16], krB[2][16];
        float psA[2], psB[2];
        // GT fill + all K loads up front (one wall).
        // NOTE: GT2 aliases W1V/W1P — all W1V/W1P reads MUST precede the
        // GT writes (per-wave LDS ops execute in program order).
        #pragma unroll
        for (int u = 0; u < 2; ++u) {
            float* A = u ? A1 : A0;
            const int wpA = __float_as_int(A[W1P + t1h*8 + kp2]);
            const int wpB = __float_as_int(A[W1P + (2+t1h)*8 + kp2]);
            psA[u] = A[W1V + t1h*8 + kp2];
            psB[u] = A[W1V + (2+t1h)*8 + kp2];
            const int gA = child64(wpA, ci2);
            const int gB = child64(wpB, ci2);
            A[GT  + t1h*32 + kk] = __int_as_float(gA);   // GT idx [0..64)
            A[GT2 + t1h*32 + kk] = __int_as_float(gB);   // GT idx [64..128)
            const float* kva = KV2h + (size_t)gA*32;
            const float* kvb = KV2h + (size_t)gB*32;
            #pragma unroll
            for (int i = 0; i < 4; ++i) {
                *(float4*)&krA[u][i*4] = *(const float4*)(kva + i*4);
                *(float4*)&krB[u][i*4] = *(const float4*)(kvb + i*4);
            }
        }
        // score pass 0 (t1 = t1h) and pass 1 (t1 = 2+t1h) per context,
        // Q read from LDS (Q2T), broadcast within each half-wave.
        #pragma unroll
        for (int u = 0; u < 2; ++u) {
            float* A = u ? A1 : A0;
            #pragma unroll
            for (int t2 = 0; t2 < 4; ++t2) {
                float sc = dot16(&A[Q2T + (t1h*4 + t2)*16], krA[u]) * 0.25f;
                const float mm = quadmax4(sc);
                const float e  = expf(sc - mm);
                const float su = quadsum4(e);
                A[t1h*144 + t2*36 + kk] = (e / su) * psA[u];
            }
            #pragma unroll
            for (int t2 = 0; t2 < 4; ++t2) {
                float sc = dot16(&A[Q2T + ((2 + t1h)*4 + t2)*16], krB[u]) * 0.25f;
                const float mm = quadmax4(sc);
                const float e  = expf(sc - mm);
                const float su = quadsum4(e);
                A[288 + t1h*144 + t2*36 + kk] = (e / su) * psB[u];
            }
        }
    }
    // msg halves per context. OUTT overlaps the score region, so both
    // h-accumulators are finished in registers before any OUTT store.
    {
        const int ks2 = lane >> 5, qq = (lane >> 2) & 7, dq = lane & 3;
        const int t1l = qq >> 2, t2 = qq & 3;
        #pragma unroll
        for (int u = 0; u < 2; ++u) {
            float* A = u ? A1 : A0;
            float4 accs[2];
            #pragma unroll
            for (int h = 0; h < 2; ++h) {
                const int t1 = h*2 + t1l;
                const int sb = (t1 >> 1)*288 + (t1 & 1)*144 + t2*36;
                const int gtb = (h == 0) ? GT : GT2;   // GT idx [0..64) / [64..128)
                float4 acc = make_float4(0.f, 0.f, 0.f, 0.f);
                #pragma unroll
                for (int j4 = 0; j4 < 4; ++j4) {
                    float4 pv = *(const float4*)&A[sb + ks2*16 + j4*4];
                    const float pa[4] = {pv.x, pv.y, pv.z, pv.w};
                    #pragma unroll
                    for (int c = 0; c < 4; ++c) {
                        const int g2 = __float_as_int(A[gtb + t1l*32 + ks2*16 + j4*4 + c]);
                        float4 vv = *(const float4*)(KV2h + (size_t)g2*32 + 16 + dq*4);
                        acc.x = fmaf(pa[c], vv.x, acc.x);
                        acc.y = fmaf(pa[c], vv.y, acc.y);
                        acc.z = fmaf(pa[c], vv.z, acc.z);
                        acc.w = fmaf(pa[c], vv.w, acc.w);
                    }
                }
                acc.x += __shfl_xor(acc.x, 32); acc.y += __shfl_xor(acc.y, 32);
                acc.z += __shfl_xor(acc.z, 32); acc.w += __shfl_xor(acc.w, 32);
                float4 m1 = *(const float4*)&A[MSG1 + t1*16 + dq*4];
                float4 m0 = *(const float4*)&A[MSG0 + dq*4];
                acc.x += m1.x + m0.x;
                acc.y += m1.y + m0.y;
                acc.z += m1.z + m0.z;
                acc.w += m1.w + m0.w;
                accs[h] = acc;
            }
            if (lane < 32) {
                *(float4*)&A[OUTT + ((t1l    )*4 + t2)*16 + dq*4] = accs[0];
                *(float4*)&A[OUTT + ((2 + t1l)*4 + t2)*16 + dq*4] = accs[1];
            }
        }
    }

    // ======== output: two adjacent 4x4 patches (same rows) ========
    {
        const int y = lane & 3, dd = lane >> 2;
        #pragma unroll
        for (int u = 0; u < 2; ++u) {
            float* A = u ? A1 : A0;
            const int W0u = W0b + u;
            float vr[4];
            #pragma unroll
            for (int x = 0; x < 4; ++x) {
                const int t1 = (((y>>1) << 1) | (x>>1));
                const int t2 = (((y&1)  << 1) | (x&1));
                vr[x] = A[OUTT + (t1*4 + t2)*16 + dd];
            }
            float* op = out + (((size_t)(b*128 + n*16 + dd)*64 + 4*H0 + y))*64 + 4*W0u;
            *(float4*)op = make_float4(vr[0], vr[1], vr[2], vr[3]);
        }
    }
}

extern "C" void kernel_launch(void* const* d_in, const int* in_sizes, int n_in,
                              void* d_out, int out_size, void* d_ws, size_t ws_size,
                              hipStream_t stream)
{
    const float* q0 = (const float*)d_in[0];
    const float* k0 = (const float*)d_in[1];
    const float* v0 = (const float*)d_in[2];
    const float* q1 = (const float*)d_in[3];
    const float* k1 = (const float*)d_in[4];
    const float* v1 = (const float*)d_in[5];
    const float* q2 = (const float*)d_in[6];
    const float* k2 = (const float*)d_in[7];
    const float* v2 = (const float*)d_in[8];

    float* ws  = (float*)d_ws;
    float* Q1h = ws;                 // 4*8*1024*16 = 524288
    float* KV1 = ws + 524288;        // 4*8*1024*32 = 1048576
    float* Q2h = ws + 1572864;       // 4*8*4096*16 = 2097152
    float* KV2 = ws + 3670016;       // 4*8*4096*32 = 4194304

    k_repack<<<dim3(60, 8, 4), 256, 0, stream>>>(q1, k1, v1, q2, k2, v2,
                                                 Q1h, KV1, Q2h, KV2);
    k_fused<<<dim3(1024, 1, 1), 256, 0, stream>>>(q0, k0, v0,
                                                  Q1h, KV1, Q2h, KV2,
                                                  (float*)d_out);
}